// Round 6
// baseline (339.979 us; speedup 1.0000x reference)
//
#include <hip/hip_runtime.h>
#include <hip/hip_bf16.h>
#include <hip/hip_fp16.h>

typedef unsigned short u16;
typedef __attribute__((ext_vector_type(8))) short short8;
typedef __attribute__((ext_vector_type(4))) short s16x4;
typedef __attribute__((ext_vector_type(8))) u16 u16x8;
typedef __attribute__((ext_vector_type(4))) u16 u16x4;
typedef __attribute__((ext_vector_type(2))) u16 u16x2;
typedef __attribute__((ext_vector_type(8))) _Float16 half8;
typedef __attribute__((ext_vector_type(4))) _Float16 half4;
typedef __attribute__((ext_vector_type(4))) float f32x4;
typedef __attribute__((ext_vector_type(2))) float f32x2;

#define NB 8
#define TQn 1024
#define TKn 4096
#define DINn 1024
#define DOUTn 256
#define NROWS (NB * TQn)
#define NKB (TKn / 128)
#define EXPSHIFT 40.0f
#define LP 36   // LDS row stride (u16) for 32-wide k tiles
#define LP2 66  // LDS row stride (u16) for 64-wide k tiles: 33 banks -> distinct within 16 lanes

#define DEV static __device__ __forceinline__

DEV u16 f2bf(float x) {
    __hip_bfloat16 h = __float2bfloat16(x);
    return *reinterpret_cast<u16*>(&h);
}
DEV float bf2f(u16 u) {
    __hip_bfloat16 h;
    *reinterpret_cast<u16*>(&h) = u;
    return __bfloat162float(h);
}
DEV void split2(float x, u16& hi, u16& lo) {
    u16 h = f2bf(x);
    float hf = bf2f(h);
    hi = h;
    lo = f2bf(x - hf);
}
DEV void split4(const float4 v, u16x4& h, u16x4& l) {
    u16 h0, l0, h1, l1, h2, l2, h3, l3;
    split2(v.x, h0, l0);
    split2(v.y, h1, l1);
    split2(v.z, h2, l2);
    split2(v.w, h3, l3);
    h = (u16x4){h0, h1, h2, h3};
    l = (u16x4){l0, l1, l2, l3};
}
DEV short8 ld8s(const u16* p) {
    s16x4 a = *reinterpret_cast<const s16x4*>(p);
    s16x4 b = *reinterpret_cast<const s16x4*>(p + 4);
    short8 r;
    r[0] = a[0]; r[1] = a[1]; r[2] = a[2]; r[3] = a[3];
    r[4] = b[0]; r[5] = b[1]; r[6] = b[2]; r[7] = b[3];
    return r;
}
DEV half8 ld8h(const u16* p) {
    half4 a = *reinterpret_cast<const half4*>(p);
    half4 b = *reinterpret_cast<const half4*>(p + 4);
    half8 r;
    r[0] = a[0]; r[1] = a[1]; r[2] = a[2]; r[3] = a[3];
    r[4] = b[0]; r[5] = b[1]; r[6] = b[2]; r[7] = b[3];
    return r;
}
DEV void st8(u16* p, u16x8 v) {
    *reinterpret_cast<u16x4*>(p) = (u16x4){v[0], v[1], v[2], v[3]};
    *reinterpret_cast<u16x4*>(p + 4) = (u16x4){v[4], v[5], v[6], v[7]};
}

// ---------------------------------------------------------------------------
// Kernel 1: transpose+convert emb [B][TK][DOUT] fp32 -> embT [B][DOUT][TK] fp16
// ---------------------------------------------------------------------------
__global__ __launch_bounds__(256) void k_embT(const float* __restrict__ emb,
                                              _Float16* __restrict__ embT) {
    __shared__ float tile[64][65];
    const int b = blockIdx.z;
    const int k0 = blockIdx.x * 64;
    const int o0 = blockIdx.y * 64;
    const int t = threadIdx.x;
    const int c = t & 63;
    const int r0 = t >> 6;
#pragma unroll
    for (int i = 0; i < 16; i++) {
        int r = r0 + i * 4;
        tile[c][r] = emb[((size_t)b * TKn + k0 + r) * DOUTn + o0 + c];
    }
    __syncthreads();
#pragma unroll
    for (int i = 0; i < 16; i++) {
        int r = r0 + i * 4;
        embT[((size_t)b * DOUTn + o0 + r) * TKn + k0 + c] = (_Float16)tile[r][c];
    }
}

// ---------------------------------------------------------------------------
// Kernel 2: linear  decsmall = dec @ W^T + b, split into hi/lo bf16
// ---------------------------------------------------------------------------
__global__ __launch_bounds__(256) void k_linear(const float* __restrict__ dec,
                                                const float* __restrict__ W,
                                                const float* __restrict__ bias,
                                                u16* __restrict__ ds_hi,
                                                u16* __restrict__ ds_lo) {
    __shared__ u16 sAh[128][LP], sAl[128][LP], sBh[64][LP], sBl[64][LP];
    const int t = threadIdx.x;
    const int m0 = blockIdx.x * 128;
    const int n0 = blockIdx.y * 64;
    const int w = t >> 6, lane = t & 63;
    const int wr = w >> 1, wc = w & 1;
    const int lr = lane & 15, g = lane >> 4, kg8 = g * 8;

    f32x4 acc[4][2];
#pragma unroll
    for (int m = 0; m < 4; m++)
#pragma unroll
        for (int n = 0; n < 2; n++) acc[m][n] = (f32x4){0.f, 0.f, 0.f, 0.f};

    for (int k0 = 0; k0 < DINn; k0 += 32) {
        __syncthreads();
#pragma unroll
        for (int i = 0; i < 4; i++) {
            int f = i * 256 + t;
            int row = f >> 3, c4 = (f & 7) * 4;
            const float4 v = *reinterpret_cast<const float4*>(
                dec + (size_t)(m0 + row) * DINn + k0 + c4);
            u16x4 h, l;
            split4(v, h, l);
            *reinterpret_cast<u16x4*>(&sAh[row][c4]) = h;
            *reinterpret_cast<u16x4*>(&sAl[row][c4]) = l;
        }
#pragma unroll
        for (int i = 0; i < 2; i++) {
            int f = i * 256 + t;
            int row = f >> 3, c4 = (f & 7) * 4;
            const float4 v = *reinterpret_cast<const float4*>(
                W + (size_t)(n0 + row) * DINn + k0 + c4);
            u16x4 h, l;
            split4(v, h, l);
            *reinterpret_cast<u16x4*>(&sBh[row][c4]) = h;
            *reinterpret_cast<u16x4*>(&sBl[row][c4]) = l;
        }
        __syncthreads();
        short8 ah[4], al[4], bh[2], bl[2];
#pragma unroll
        for (int m = 0; m < 4; m++) {
            int row = wr * 64 + m * 16 + lr;
            ah[m] = ld8s(&sAh[row][kg8]);
            al[m] = ld8s(&sAl[row][kg8]);
        }
#pragma unroll
        for (int n = 0; n < 2; n++) {
            int row = wc * 32 + n * 16 + lr;
            bh[n] = ld8s(&sBh[row][kg8]);
            bl[n] = ld8s(&sBl[row][kg8]);
        }
#pragma unroll
        for (int m = 0; m < 4; m++)
#pragma unroll
            for (int n = 0; n < 2; n++) {
                acc[m][n] = __builtin_amdgcn_mfma_f32_16x16x32_bf16(ah[m], bh[n], acc[m][n], 0, 0, 0);
                acc[m][n] = __builtin_amdgcn_mfma_f32_16x16x32_bf16(ah[m], bl[n], acc[m][n], 0, 0, 0);
                acc[m][n] = __builtin_amdgcn_mfma_f32_16x16x32_bf16(al[m], bh[n], acc[m][n], 0, 0, 0);
            }
    }
#pragma unroll
    for (int m = 0; m < 4; m++) {
#pragma unroll
        for (int n = 0; n < 2; n++) {
            int colg = n0 + wc * 32 + n * 16 + lr;
            float bv = bias[colg];
#pragma unroll
            for (int r = 0; r < 4; r++) {
                int rowg = m0 + wr * 64 + m * 16 + g * 4 + r;
                float v = acc[m][n][r] + bv;
                u16 h, l;
                split2(v, h, l);
                ds_hi[(size_t)rowg * DOUTn + colg] = h;
                ds_lo[(size_t)rowg * DOUTn + colg] = l;
            }
        }
    }
}

// ---------------------------------------------------------------------------
// Kernel 3: scores GEMM (split 3-MFMA) + mask + p_u = exp(s - 40) nt-write
//           + per-row partial sums -> partsum[kb][row]
// ---------------------------------------------------------------------------
__global__ __launch_bounds__(256) void k_scores_exp(const u16* __restrict__ ds_hi,
                                                    const u16* __restrict__ ds_lo,
                                                    const float* __restrict__ emb,
                                                    const int* __restrict__ emask,
                                                    float* __restrict__ attn,
                                                    float* __restrict__ partsum) {
    __shared__ u16 sAh[128][LP], sAl[128][LP], sBh[128][LP], sBl[128][LP];
    __shared__ float sSum[2][128];
    const int t = threadIdx.x;
    const int flat = blockIdx.x + 8 * (blockIdx.y + 32 * blockIdx.z);
    const int b = flat & 7;
    const int rest = flat >> 3;
    const int kb = rest & 31;
    const int q0 = (rest >> 5) * 128;
    const int kb0 = kb * 128;
    const int w = t >> 6, lane = t & 63;
    const int wr = w >> 1, wc = w & 1;
    const int lr = lane & 15, g = lane >> 4, kg8 = g * 8;

    f32x4 acc[4][4];
#pragma unroll
    for (int m = 0; m < 4; m++)
#pragma unroll
        for (int n = 0; n < 4; n++) acc[m][n] = (f32x4){0.f, 0.f, 0.f, 0.f};

    for (int o0 = 0; o0 < DOUTn; o0 += 32) {
        __syncthreads();
#pragma unroll
        for (int i = 0; i < 2; i++) {
            int f8 = i * 256 + t;
            int row = f8 >> 2, c8 = (f8 & 3) * 8;
            size_t src = (size_t)(b * TQn + q0 + row) * DOUTn + o0 + c8;
            st8(&sAh[row][c8], *reinterpret_cast<const u16x8*>(ds_hi + src));
            st8(&sAl[row][c8], *reinterpret_cast<const u16x8*>(ds_lo + src));
        }
#pragma unroll
        for (int i = 0; i < 4; i++) {
            int f = i * 256 + t;
            int row = f >> 3, c4 = (f & 7) * 4;
            const float4 v = *reinterpret_cast<const float4*>(
                emb + (size_t)(b * TKn + kb0 + row) * DOUTn + o0 + c4);
            u16x4 h, l;
            split4(v, h, l);
            *reinterpret_cast<u16x4*>(&sBh[row][c4]) = h;
            *reinterpret_cast<u16x4*>(&sBl[row][c4]) = l;
        }
        __syncthreads();
        short8 ah[4], al[4], bh[4], bl[4];
#pragma unroll
        for (int m = 0; m < 4; m++) {
            int row = wr * 64 + m * 16 + lr;
            ah[m] = ld8s(&sAh[row][kg8]);
            al[m] = ld8s(&sAl[row][kg8]);
        }
#pragma unroll
        for (int n = 0; n < 4; n++) {
            int row = wc * 64 + n * 16 + lr;
            bh[n] = ld8s(&sBh[row][kg8]);
            bl[n] = ld8s(&sBl[row][kg8]);
        }
#pragma unroll
        for (int m = 0; m < 4; m++)
#pragma unroll
            for (int n = 0; n < 4; n++) {
                acc[m][n] = __builtin_amdgcn_mfma_f32_16x16x32_bf16(ah[m], bh[n], acc[m][n], 0, 0, 0);
                acc[m][n] = __builtin_amdgcn_mfma_f32_16x16x32_bf16(ah[m], bl[n], acc[m][n], 0, 0, 0);
                acc[m][n] = __builtin_amdgcn_mfma_f32_16x16x32_bf16(al[m], bh[n], acc[m][n], 0, 0, 0);
            }
    }
    const int* em = emask + (size_t)b * TKn;
    float* pout = attn + ((size_t)(b * TQn + q0)) * TKn + kb0;
    float rowAcc[4][4];
#pragma unroll
    for (int m = 0; m < 4; m++)
#pragma unroll
        for (int r = 0; r < 4; r++) rowAcc[m][r] = 0.f;

#pragma unroll
    for (int n = 0; n < 4; n++) {
        int colL = wc * 64 + n * 16 + lr;
        int mk = em[kb0 + colL];
#pragma unroll
        for (int m = 0; m < 4; m++) {
#pragma unroll
            for (int r = 0; r < 4; r++) {
                int rowL = wr * 64 + m * 16 + g * 4 + r;
                float p = mk ? __expf(acc[m][n][r] - EXPSHIFT) : 0.f;
                __builtin_nontemporal_store(p, &pout[(size_t)rowL * TKn + colL]);
                rowAcc[m][r] += p;
            }
        }
    }
#pragma unroll
    for (int m = 0; m < 4; m++) {
#pragma unroll
        for (int r = 0; r < 4; r++) {
            float v = rowAcc[m][r];
            v += __shfl_xor(v, 1);
            v += __shfl_xor(v, 2);
            v += __shfl_xor(v, 4);
            v += __shfl_xor(v, 8);
            if (lr == 0) sSum[wc][wr * 64 + m * 16 + g * 4 + r] = v;
        }
    }
    __syncthreads();
    if (t < 128) {
        partsum[(size_t)kb * NROWS + (size_t)b * TQn + q0 + t] =
            sSum[0][t] + sSum[1][t];
    }
}

// ---------------------------------------------------------------------------
// Kernel 4: inv_sum[row] = 1 / sum_kb partsum[kb][row]
// ---------------------------------------------------------------------------
__global__ __launch_bounds__(256) void k_rowsum(const float* __restrict__ partsum,
                                                float* __restrict__ inv_sum) {
    int row = blockIdx.x * 256 + threadIdx.x;
    float s = 0.f;
#pragma unroll
    for (int kb = 0; kb < NKB; kb++) s += partsum[(size_t)kb * NROWS + row];
    inv_sum[row] = 1.0f / s;
}

// ---------------------------------------------------------------------------
// Kernel 5: PV GEMM, split-K x4. Block: 64 q-rows x 256 o x K-chunk 1024.
// 256 threads (4 waves; wave w owns cols w*64..w*64+63, all 64 rows).
// K-step 64: stage A = p_u*inv (nt-write final attn, cvt fp16 to LDS),
// stage B = embT fp16; 32 MFMA/wave per step. Writes partial[kc].
// XCD decode: flat%8 = batch.
// ---------------------------------------------------------------------------
__global__ __launch_bounds__(256) void k_pv4(float* __restrict__ attn,
                                             const _Float16* __restrict__ embT,
                                             const float* __restrict__ inv_sum,
                                             float* __restrict__ partial) {
    __shared__ u16 sA[64][LP2];   // fp16 bits, 64 rows x 64 k
    __shared__ u16 sB[256][LP2];  // fp16 bits, 256 o x 64 k
    __shared__ float sInv[64];
    const int t = threadIdx.x;
    const int flat = blockIdx.x + 16 * blockIdx.y + 64 * blockIdx.z;  // 0..511
    const int b = flat & 7;
    const int rest = flat >> 3;
    const int kc = rest & 3;
    const int q0 = (rest >> 2) * 64;
    const int w = t >> 6, lane = t & 63;
    const int lr = lane & 15, g = lane >> 4, kg8 = g * 8;
    const int kbase = kc * 1024;
    const size_t rowBase = (size_t)b * TQn + q0;
    const u16* ebt = reinterpret_cast<const u16*>(embT);

    if (t < 64) sInv[t] = inv_sum[rowBase + t];

    f32x4 acc[4][4];
#pragma unroll
    for (int m = 0; m < 4; m++)
#pragma unroll
        for (int n = 0; n < 4; n++) acc[m][n] = (f32x4){0.f, 0.f, 0.f, 0.f};

    for (int ks = 0; ks < 1024; ks += 64) {
        __syncthreads();
        // stage A: 64 rows x 64 k fp32 p_u; scale, nt-write attn, cvt fp16
#pragma unroll
        for (int i = 0; i < 4; i++) {
            int f = i * 256 + t;
            int row = f >> 4, c4 = (f & 15) * 4;
            size_t gaddr = (rowBase + row) * TKn + kbase + ks + c4;
            f32x4 v = *reinterpret_cast<const f32x4*>(attn + gaddr);
            v = v * sInv[row];
            __builtin_nontemporal_store(v, reinterpret_cast<f32x4*>(attn + gaddr));
            u16x4 hv;
            hv[0] = __builtin_bit_cast(u16, (_Float16)v[0]);
            hv[1] = __builtin_bit_cast(u16, (_Float16)v[1]);
            hv[2] = __builtin_bit_cast(u16, (_Float16)v[2]);
            hv[3] = __builtin_bit_cast(u16, (_Float16)v[3]);
            *reinterpret_cast<u16x4*>(&sA[row][c4]) = hv;
        }
        // stage B: 256 o x 64 k fp16 from embT
#pragma unroll
        for (int i = 0; i < 8; i++) {
            int f = i * 256 + t;
            int row = f >> 3, c8 = (f & 7) * 8;
            st8(&sB[row][c8], *reinterpret_cast<const u16x8*>(
                                  ebt + (size_t)(b * DOUTn + row) * TKn + kbase + ks + c8));
        }
        __syncthreads();
#pragma unroll
        for (int kk = 0; kk < 2; kk++) {
            half8 a[4], bb[4];
#pragma unroll
            for (int m = 0; m < 4; m++)
                a[m] = ld8h(&sA[m * 16 + lr][kk * 32 + kg8]);
#pragma unroll
            for (int n = 0; n < 4; n++)
                bb[n] = ld8h(&sB[w * 64 + n * 16 + lr][kk * 32 + kg8]);
#pragma unroll
            for (int m = 0; m < 4; m++)
#pragma unroll
                for (int n = 0; n < 4; n++)
                    acc[m][n] = __builtin_amdgcn_mfma_f32_16x16x32_f16(a[m], bb[n], acc[m][n], 0, 0, 0);
        }
    }
    // epilogue: partial[kc][row][col]
#pragma unroll
    for (int m = 0; m < 4; m++) {
#pragma unroll
        for (int n = 0; n < 4; n++) {
            int col = w * 64 + n * 16 + lr;
#pragma unroll
            for (int r = 0; r < 4; r++) {
                size_t grow = rowBase + m * 16 + g * 4 + r;
                partial[((size_t)kc * NROWS + grow) * DOUTn + col] = acc[m][n][r];
            }
        }
    }
}

// ---------------------------------------------------------------------------
// Kernel 6: out = sum of 4 partials
// ---------------------------------------------------------------------------
__global__ __launch_bounds__(256) void k_reduce(const float* __restrict__ partial,
                                                float* __restrict__ out) {
    const size_t stride = (size_t)NROWS * DOUTn;
    size_t i = ((size_t)blockIdx.x * 256 + threadIdx.x) * 4;
    f32x4 a0 = *reinterpret_cast<const f32x4*>(partial + i);
    f32x4 a1 = *reinterpret_cast<const f32x4*>(partial + stride + i);
    f32x4 a2 = *reinterpret_cast<const f32x4*>(partial + 2 * stride + i);
    f32x4 a3 = *reinterpret_cast<const f32x4*>(partial + 3 * stride + i);
    f32x4 s = (a0 + a1) + (a2 + a3);
    *reinterpret_cast<f32x4*>(out + i) = s;
}

// ---------------------------------------------------------------------------
extern "C" void kernel_launch(void* const* d_in, const int* in_sizes, int n_in,
                              void* d_out, int out_size, void* d_ws, size_t ws_size,
                              hipStream_t stream) {
    const float* dec = (const float*)d_in[0];
    const float* emb = (const float*)d_in[1];
    const int* emask = (const int*)d_in[2];
    const float* W = (const float*)d_in[3];
    const float* bias = (const float*)d_in[4];

    float* out = (float*)d_out;
    float* attn = out + (size_t)NROWS * DOUTn;

    char* wsb = (char*)d_ws;
    u16* ds_hi = (u16*)wsb;
    wsb += (size_t)NROWS * DOUTn * 2;
    u16* ds_lo = (u16*)wsb;
    wsb += (size_t)NROWS * DOUTn * 2;
    _Float16* embT = (_Float16*)wsb;
    wsb += (size_t)NB * DOUTn * TKn * 2;
    float* inv_sum = (float*)wsb;
    wsb += (size_t)NROWS * 4;
    float* partsum = (float*)wsb;
    wsb += (size_t)NKB * NROWS * 4;
    float* partial = (float*)wsb;  // 4 * 8192 * 256 fp32 = 33.5 MB

    k_embT<<<dim3(TKn / 64, DOUTn / 64, NB), 256, 0, stream>>>(emb, embT);
    k_linear<<<dim3(NROWS / 128, DOUTn / 64), 256, 0, stream>>>(dec, W, bias, ds_hi, ds_lo);
    k_scores_exp<<<dim3(TQn / 128, NKB, NB), 256, 0, stream>>>(ds_hi, ds_lo, emb, emask, attn, partsum);
    k_rowsum<<<dim3(NROWS / 256), 256, 0, stream>>>(partsum, inv_sum);
    k_pv4<<<dim3(16, 4, 8), 256, 0, stream>>>(attn, embT, inv_sum, partial);
    k_reduce<<<dim3((NROWS * DOUTn / 4) / 256), 256, 0, stream>>>(partial, out);
}

// Round 7
// 269.198 us; speedup vs baseline: 1.2629x; 1.2629x over previous
//
#include <hip/hip_runtime.h>
#include <hip/hip_bf16.h>
#include <hip/hip_fp16.h>

typedef unsigned short u16;
typedef __attribute__((ext_vector_type(8))) short short8;
typedef __attribute__((ext_vector_type(4))) short s16x4;
typedef __attribute__((ext_vector_type(8))) u16 u16x8;
typedef __attribute__((ext_vector_type(4))) u16 u16x4;
typedef __attribute__((ext_vector_type(2))) u16 u16x2;
typedef __attribute__((ext_vector_type(8))) _Float16 half8;
typedef __attribute__((ext_vector_type(4))) _Float16 half4;
typedef __attribute__((ext_vector_type(4))) float f32x4;
typedef __attribute__((ext_vector_type(2))) float f32x2;

#define NB 8
#define TQn 1024
#define TKn 4096
#define DINn 1024
#define DOUTn 256
#define NROWS (NB * TQn)
#define NKB (TKn / 128)
#define EXPSHIFT 40.0f
#define LP 36   // LDS row stride (u16), 72 B

#define DEV static __device__ __forceinline__

DEV u16 f2bf(float x) {
    __hip_bfloat16 h = __float2bfloat16(x);
    return *reinterpret_cast<u16*>(&h);
}
DEV float bf2f(u16 u) {
    __hip_bfloat16 h;
    *reinterpret_cast<u16*>(&h) = u;
    return __bfloat162float(h);
}
DEV void split2(float x, u16& hi, u16& lo) {
    u16 h = f2bf(x);
    float hf = bf2f(h);
    hi = h;
    lo = f2bf(x - hf);
}
DEV void split4(const float4 v, u16x4& h, u16x4& l) {
    u16 h0, l0, h1, l1, h2, l2, h3, l3;
    split2(v.x, h0, l0);
    split2(v.y, h1, l1);
    split2(v.z, h2, l2);
    split2(v.w, h3, l3);
    h = (u16x4){h0, h1, h2, h3};
    l = (u16x4){l0, l1, l2, l3};
}
DEV short8 ld8s(const u16* p) {
    s16x4 a = *reinterpret_cast<const s16x4*>(p);
    s16x4 b = *reinterpret_cast<const s16x4*>(p + 4);
    short8 r;
    r[0] = a[0]; r[1] = a[1]; r[2] = a[2]; r[3] = a[3];
    r[4] = b[0]; r[5] = b[1]; r[6] = b[2]; r[7] = b[3];
    return r;
}
DEV half8 ld8h(const u16* p) {
    half4 a = *reinterpret_cast<const half4*>(p);
    half4 b = *reinterpret_cast<const half4*>(p + 4);
    half8 r;
    r[0] = a[0]; r[1] = a[1]; r[2] = a[2]; r[3] = a[3];
    r[4] = b[0]; r[5] = b[1]; r[6] = b[2]; r[7] = b[3];
    return r;
}
DEV void st8(u16* p, u16x8 v) {
    *reinterpret_cast<u16x4*>(p) = (u16x4){v[0], v[1], v[2], v[3]};
    *reinterpret_cast<u16x4*>(p + 4) = (u16x4){v[4], v[5], v[6], v[7]};
}

// ---------------------------------------------------------------------------
// Kernel 1: transpose+convert emb [B][TK][DOUT] fp32 -> embT [B][DOUT][TK] fp16
// ---------------------------------------------------------------------------
__global__ __launch_bounds__(256) void k_embT(const float* __restrict__ emb,
                                              _Float16* __restrict__ embT) {
    __shared__ float tile[64][65];
    const int b = blockIdx.z;
    const int k0 = blockIdx.x * 64;
    const int o0 = blockIdx.y * 64;
    const int t = threadIdx.x;
    const int c = t & 63;
    const int r0 = t >> 6;
#pragma unroll
    for (int i = 0; i < 16; i++) {
        int r = r0 + i * 4;
        tile[c][r] = emb[((size_t)b * TKn + k0 + r) * DOUTn + o0 + c];
    }
    __syncthreads();
#pragma unroll
    for (int i = 0; i < 16; i++) {
        int r = r0 + i * 4;
        embT[((size_t)b * DOUTn + o0 + r) * TKn + k0 + c] = (_Float16)tile[r][c];
    }
}

// ---------------------------------------------------------------------------
// Kernel 2: linear  decsmall = dec @ W^T + b, split into hi/lo bf16
// ---------------------------------------------------------------------------
__global__ __launch_bounds__(256) void k_linear(const float* __restrict__ dec,
                                                const float* __restrict__ W,
                                                const float* __restrict__ bias,
                                                u16* __restrict__ ds_hi,
                                                u16* __restrict__ ds_lo) {
    __shared__ u16 sAh[128][LP], sAl[128][LP], sBh[64][LP], sBl[64][LP];
    const int t = threadIdx.x;
    const int m0 = blockIdx.x * 128;
    const int n0 = blockIdx.y * 64;
    const int w = t >> 6, lane = t & 63;
    const int wr = w >> 1, wc = w & 1;
    const int lr = lane & 15, g = lane >> 4, kg8 = g * 8;

    f32x4 acc[4][2];
#pragma unroll
    for (int m = 0; m < 4; m++)
#pragma unroll
        for (int n = 0; n < 2; n++) acc[m][n] = (f32x4){0.f, 0.f, 0.f, 0.f};

    for (int k0 = 0; k0 < DINn; k0 += 32) {
        __syncthreads();
#pragma unroll
        for (int i = 0; i < 4; i++) {
            int f = i * 256 + t;
            int row = f >> 3, c4 = (f & 7) * 4;
            const float4 v = *reinterpret_cast<const float4*>(
                dec + (size_t)(m0 + row) * DINn + k0 + c4);
            u16x4 h, l;
            split4(v, h, l);
            *reinterpret_cast<u16x4*>(&sAh[row][c4]) = h;
            *reinterpret_cast<u16x4*>(&sAl[row][c4]) = l;
        }
#pragma unroll
        for (int i = 0; i < 2; i++) {
            int f = i * 256 + t;
            int row = f >> 3, c4 = (f & 7) * 4;
            const float4 v = *reinterpret_cast<const float4*>(
                W + (size_t)(n0 + row) * DINn + k0 + c4);
            u16x4 h, l;
            split4(v, h, l);
            *reinterpret_cast<u16x4*>(&sBh[row][c4]) = h;
            *reinterpret_cast<u16x4*>(&sBl[row][c4]) = l;
        }
        __syncthreads();
        short8 ah[4], al[4], bh[2], bl[2];
#pragma unroll
        for (int m = 0; m < 4; m++) {
            int row = wr * 64 + m * 16 + lr;
            ah[m] = ld8s(&sAh[row][kg8]);
            al[m] = ld8s(&sAl[row][kg8]);
        }
#pragma unroll
        for (int n = 0; n < 2; n++) {
            int row = wc * 32 + n * 16 + lr;
            bh[n] = ld8s(&sBh[row][kg8]);
            bl[n] = ld8s(&sBl[row][kg8]);
        }
#pragma unroll
        for (int m = 0; m < 4; m++)
#pragma unroll
            for (int n = 0; n < 2; n++) {
                acc[m][n] = __builtin_amdgcn_mfma_f32_16x16x32_bf16(ah[m], bh[n], acc[m][n], 0, 0, 0);
                acc[m][n] = __builtin_amdgcn_mfma_f32_16x16x32_bf16(ah[m], bl[n], acc[m][n], 0, 0, 0);
                acc[m][n] = __builtin_amdgcn_mfma_f32_16x16x32_bf16(al[m], bh[n], acc[m][n], 0, 0, 0);
            }
    }
#pragma unroll
    for (int m = 0; m < 4; m++) {
#pragma unroll
        for (int n = 0; n < 2; n++) {
            int colg = n0 + wc * 32 + n * 16 + lr;
            float bv = bias[colg];
#pragma unroll
            for (int r = 0; r < 4; r++) {
                int rowg = m0 + wr * 64 + m * 16 + g * 4 + r;
                float v = acc[m][n][r] + bv;
                u16 h, l;
                split2(v, h, l);
                ds_hi[(size_t)rowg * DOUTn + colg] = h;
                ds_lo[(size_t)rowg * DOUTn + colg] = l;
            }
        }
    }
}

// ---------------------------------------------------------------------------
// Kernel 3: scores GEMM (split 3-MFMA) + mask + p_u = exp(s - 40) nt-write
//           + per-row partial sums -> partsum[kb][row]
// ---------------------------------------------------------------------------
__global__ __launch_bounds__(256) void k_scores_exp(const u16* __restrict__ ds_hi,
                                                    const u16* __restrict__ ds_lo,
                                                    const float* __restrict__ emb,
                                                    const int* __restrict__ emask,
                                                    float* __restrict__ attn,
                                                    float* __restrict__ partsum) {
    __shared__ u16 sAh[128][LP], sAl[128][LP], sBh[128][LP], sBl[128][LP];
    __shared__ float sSum[2][128];
    const int t = threadIdx.x;
    const int flat = blockIdx.x + 8 * (blockIdx.y + 32 * blockIdx.z);
    const int b = flat & 7;
    const int rest = flat >> 3;
    const int kb = rest & 31;
    const int q0 = (rest >> 5) * 128;
    const int kb0 = kb * 128;
    const int w = t >> 6, lane = t & 63;
    const int wr = w >> 1, wc = w & 1;
    const int lr = lane & 15, g = lane >> 4, kg8 = g * 8;

    f32x4 acc[4][4];
#pragma unroll
    for (int m = 0; m < 4; m++)
#pragma unroll
        for (int n = 0; n < 4; n++) acc[m][n] = (f32x4){0.f, 0.f, 0.f, 0.f};

    for (int o0 = 0; o0 < DOUTn; o0 += 32) {
        __syncthreads();
#pragma unroll
        for (int i = 0; i < 2; i++) {
            int f8 = i * 256 + t;
            int row = f8 >> 2, c8 = (f8 & 3) * 8;
            size_t src = (size_t)(b * TQn + q0 + row) * DOUTn + o0 + c8;
            st8(&sAh[row][c8], *reinterpret_cast<const u16x8*>(ds_hi + src));
            st8(&sAl[row][c8], *reinterpret_cast<const u16x8*>(ds_lo + src));
        }
#pragma unroll
        for (int i = 0; i < 4; i++) {
            int f = i * 256 + t;
            int row = f >> 3, c4 = (f & 7) * 4;
            const float4 v = *reinterpret_cast<const float4*>(
                emb + (size_t)(b * TKn + kb0 + row) * DOUTn + o0 + c4);
            u16x4 h, l;
            split4(v, h, l);
            *reinterpret_cast<u16x4*>(&sBh[row][c4]) = h;
            *reinterpret_cast<u16x4*>(&sBl[row][c4]) = l;
        }
        __syncthreads();
        short8 ah[4], al[4], bh[4], bl[4];
#pragma unroll
        for (int m = 0; m < 4; m++) {
            int row = wr * 64 + m * 16 + lr;
            ah[m] = ld8s(&sAh[row][kg8]);
            al[m] = ld8s(&sAl[row][kg8]);
        }
#pragma unroll
        for (int n = 0; n < 4; n++) {
            int row = wc * 64 + n * 16 + lr;
            bh[n] = ld8s(&sBh[row][kg8]);
            bl[n] = ld8s(&sBl[row][kg8]);
        }
#pragma unroll
        for (int m = 0; m < 4; m++)
#pragma unroll
            for (int n = 0; n < 4; n++) {
                acc[m][n] = __builtin_amdgcn_mfma_f32_16x16x32_bf16(ah[m], bh[n], acc[m][n], 0, 0, 0);
                acc[m][n] = __builtin_amdgcn_mfma_f32_16x16x32_bf16(ah[m], bl[n], acc[m][n], 0, 0, 0);
                acc[m][n] = __builtin_amdgcn_mfma_f32_16x16x32_bf16(al[m], bh[n], acc[m][n], 0, 0, 0);
            }
    }
    const int* em = emask + (size_t)b * TKn;
    float* pout = attn + ((size_t)(b * TQn + q0)) * TKn + kb0;
    float rowAcc[4][4];
#pragma unroll
    for (int m = 0; m < 4; m++)
#pragma unroll
        for (int r = 0; r < 4; r++) rowAcc[m][r] = 0.f;

#pragma unroll
    for (int n = 0; n < 4; n++) {
        int colL = wc * 64 + n * 16 + lr;
        int mk = em[kb0 + colL];
#pragma unroll
        for (int m = 0; m < 4; m++) {
#pragma unroll
            for (int r = 0; r < 4; r++) {
                int rowL = wr * 64 + m * 16 + g * 4 + r;
                float p = mk ? __expf(acc[m][n][r] - EXPSHIFT) : 0.f;
                __builtin_nontemporal_store(p, &pout[(size_t)rowL * TKn + colL]);
                rowAcc[m][r] += p;
            }
        }
    }
#pragma unroll
    for (int m = 0; m < 4; m++) {
#pragma unroll
        for (int r = 0; r < 4; r++) {
            float v = rowAcc[m][r];
            v += __shfl_xor(v, 1);
            v += __shfl_xor(v, 2);
            v += __shfl_xor(v, 4);
            v += __shfl_xor(v, 8);
            if (lr == 0) sSum[wc][wr * 64 + m * 16 + g * 4 + r] = v;
        }
    }
    __syncthreads();
    if (t < 128) {
        partsum[(size_t)kb * NROWS + (size_t)b * TQn + q0 + t] =
            sSum[0][t] + sSum[1][t];
    }
}

// ---------------------------------------------------------------------------
// Kernel 4: inv_sum[row] = 1 / sum_kb partsum[kb][row]
// ---------------------------------------------------------------------------
__global__ __launch_bounds__(256) void k_rowsum(const float* __restrict__ partsum,
                                                float* __restrict__ inv_sum) {
    int row = blockIdx.x * 256 + threadIdx.x;
    float s = 0.f;
#pragma unroll
    for (int kb = 0; kb < NKB; kb++) s += partsum[(size_t)kb * NROWS + row];
    inv_sum[row] = 1.0f / s;
}

// ---------------------------------------------------------------------------
// Kernel 5: PV GEMM, PURE READ main loop (no stores inside -> no vmcnt-store
// drain at barriers). Block: 32 q x 256 o x K-chunk 1024 (split-K x4).
// 256 thr, 4 waves (wave w: cols w*64.., all 32 rows). K-step 32 with
// register double-buffer prefetch. A = p_u * inv (from sInv), cvt fp16.
// Grid 1024 blocks; XCD decode flat%8 = b. Writes partial[kc] in epilogue.
// ---------------------------------------------------------------------------
__global__ __launch_bounds__(256) void k_pv5(const float* __restrict__ attn,
                                             const _Float16* __restrict__ embT,
                                             const float* __restrict__ inv_sum,
                                             float* __restrict__ partial) {
    __shared__ u16 sA[32][LP];    // fp16 bits, 32 q x 32 k
    __shared__ u16 sB[256][LP];   // fp16 bits, 256 o x 32 k
    __shared__ float sInv[32];
    const int t = threadIdx.x;
    const int flat = blockIdx.x + 8 * (blockIdx.y + 4 * blockIdx.z);
    const int b = flat & 7;
    const int rest = flat >> 3;
    const int kc = rest & 3;
    const int q0 = (rest >> 2) * 32;
    const int w = t >> 6, lane = t & 63;
    const int lr = lane & 15, g = lane >> 4, kg8 = g * 8;
    const int kbase = kc * 1024;
    const size_t rowBase = (size_t)b * TQn + q0;
    const u16* ebt = reinterpret_cast<const u16*>(embT);

    if (t < 32) sInv[t] = inv_sum[rowBase + t];

    // staging assignments
    const int arow = t >> 3, ac4 = (t & 7) * 4;  // A: 32 rows x 32 k fp32
    const float* pA = attn + (rowBase + arow) * TKn + kbase + ac4;

    f32x4 acc[2][4];
#pragma unroll
    for (int m = 0; m < 2; m++)
#pragma unroll
        for (int n = 0; n < 4; n++) acc[m][n] = (f32x4){0.f, 0.f, 0.f, 0.f};

    // prologue: prefetch tile 0
    f32x4 pa = *reinterpret_cast<const f32x4*>(pA);
    u16x8 pb[4];
#pragma unroll
    for (int i = 0; i < 4; i++) {
        int f = i * 256 + t;
        int brow = f >> 2, bc8 = (f & 3) * 8;
        pb[i] = *reinterpret_cast<const u16x8*>(
            ebt + (size_t)(b * DOUTn + brow) * TKn + kbase + bc8);
    }

    const int NIT = 1024 / 32;
    for (int it = 0; it < NIT; it++) {
        __syncthreads();  // previous compute done; LDS writable
        // commit staged regs to LDS (A: scale + cvt fp16)
        {
            float inv = sInv[arow];
            f32x4 v = pa * inv;
            u16x4 hv;
            hv[0] = __builtin_bit_cast(u16, (_Float16)v[0]);
            hv[1] = __builtin_bit_cast(u16, (_Float16)v[1]);
            hv[2] = __builtin_bit_cast(u16, (_Float16)v[2]);
            hv[3] = __builtin_bit_cast(u16, (_Float16)v[3]);
            *reinterpret_cast<u16x4*>(&sA[arow][ac4]) = hv;
        }
#pragma unroll
        for (int i = 0; i < 4; i++) {
            int f = i * 256 + t;
            int brow = f >> 2, bc8 = (f & 3) * 8;
            st8(&sB[brow][bc8], pb[i]);
        }
        __syncthreads();  // LDS ready
        // prefetch next tile (loads overlap with compute below)
        if (it + 1 < NIT) {
            int ks = (it + 1) * 32;
            pa = *reinterpret_cast<const f32x4*>(pA + ks);
#pragma unroll
            for (int i = 0; i < 4; i++) {
                int f = i * 256 + t;
                int brow = f >> 2, bc8 = (f & 3) * 8;
                pb[i] = *reinterpret_cast<const u16x8*>(
                    ebt + (size_t)(b * DOUTn + brow) * TKn + kbase + ks + bc8);
            }
        }
        // compute: 8 MFMA per wave
        half8 a[2], bb[4];
#pragma unroll
        for (int m = 0; m < 2; m++) a[m] = ld8h(&sA[m * 16 + lr][kg8]);
#pragma unroll
        for (int n = 0; n < 4; n++) bb[n] = ld8h(&sB[w * 64 + n * 16 + lr][kg8]);
#pragma unroll
        for (int m = 0; m < 2; m++)
#pragma unroll
            for (int n = 0; n < 4; n++)
                acc[m][n] = __builtin_amdgcn_mfma_f32_16x16x32_f16(a[m], bb[n], acc[m][n], 0, 0, 0);
    }
    // epilogue: partial[kc][row][col]
#pragma unroll
    for (int m = 0; m < 2; m++) {
#pragma unroll
        for (int n = 0; n < 4; n++) {
            int col = w * 64 + n * 16 + lr;
#pragma unroll
            for (int r = 0; r < 4; r++) {
                size_t grow = rowBase + m * 16 + g * 4 + r;
                partial[((size_t)kc * NROWS + grow) * DOUTn + col] = acc[m][n][r];
            }
        }
    }
}

// ---------------------------------------------------------------------------
// Kernel 6: attn[row][k] *= inv[row]   (streaming normalize, 268 MB)
// ---------------------------------------------------------------------------
__global__ __launch_bounds__(256) void k_norm(float* __restrict__ attn,
                                              const float* __restrict__ inv_sum) {
    const size_t total4 = (size_t)NROWS * TKn / 4;
    size_t i4 = (size_t)blockIdx.x * 256 + threadIdx.x;
    const size_t stride = (size_t)gridDim.x * 256;
    for (; i4 < total4; i4 += stride) {
        int row = (int)(i4 >> 10);  // 4096 cols / 4 per vec
        f32x4 v = *reinterpret_cast<const f32x4*>(attn + i4 * 4);
        v = v * inv_sum[row];
        __builtin_nontemporal_store(v, reinterpret_cast<f32x4*>(attn + i4 * 4));
    }
}

// ---------------------------------------------------------------------------
// Kernel 7: out = sum of 4 partials
// ---------------------------------------------------------------------------
__global__ __launch_bounds__(256) void k_reduce(const float* __restrict__ partial,
                                                float* __restrict__ out) {
    const size_t stride = (size_t)NROWS * DOUTn;
    size_t i = ((size_t)blockIdx.x * 256 + threadIdx.x) * 4;
    f32x4 a0 = *reinterpret_cast<const f32x4*>(partial + i);
    f32x4 a1 = *reinterpret_cast<const f32x4*>(partial + stride + i);
    f32x4 a2 = *reinterpret_cast<const f32x4*>(partial + 2 * stride + i);
    f32x4 a3 = *reinterpret_cast<const f32x4*>(partial + 3 * stride + i);
    f32x4 s = (a0 + a1) + (a2 + a3);
    *reinterpret_cast<f32x4*>(out + i) = s;
}

// ---------------------------------------------------------------------------
extern "C" void kernel_launch(void* const* d_in, const int* in_sizes, int n_in,
                              void* d_out, int out_size, void* d_ws, size_t ws_size,
                              hipStream_t stream) {
    const float* dec = (const float*)d_in[0];
    const float* emb = (const float*)d_in[1];
    const int* emask = (const int*)d_in[2];
    const float* W = (const float*)d_in[3];
    const float* bias = (const float*)d_in[4];

    float* out = (float*)d_out;
    float* attn = out + (size_t)NROWS * DOUTn;

    char* wsb = (char*)d_ws;
    u16* ds_hi = (u16*)wsb;
    wsb += (size_t)NROWS * DOUTn * 2;
    u16* ds_lo = (u16*)wsb;
    wsb += (size_t)NROWS * DOUTn * 2;
    _Float16* embT = (_Float16*)wsb;
    wsb += (size_t)NB * DOUTn * TKn * 2;
    float* inv_sum = (float*)wsb;
    wsb += (size_t)NROWS * 4;
    float* partsum = (float*)wsb;
    wsb += (size_t)NKB * NROWS * 4;
    float* partial = (float*)wsb;  // 4 * 8192 * 256 fp32 = 33.5 MB

    k_embT<<<dim3(TKn / 64, DOUTn / 64, NB), 256, 0, stream>>>(emb, embT);
    k_linear<<<dim3(NROWS / 128, DOUTn / 64), 256, 0, stream>>>(dec, W, bias, ds_hi, ds_lo);
    k_scores_exp<<<dim3(TQn / 128, NKB, NB), 256, 0, stream>>>(ds_hi, ds_lo, emb, emask, attn, partsum);
    k_rowsum<<<dim3(NROWS / 256), 256, 0, stream>>>(partsum, inv_sum);
    k_pv5<<<dim3(8, 4, 32), 256, 0, stream>>>(attn, embT, inv_sum, partial);
    k_norm<<<dim3(2048), 256, 0, stream>>>(attn, inv_sum);
    k_reduce<<<dim3((NROWS * DOUTn / 4) / 256), 256, 0, stream>>>(partial, out);
}

// Round 8
// 232.148 us; speedup vs baseline: 1.4645x; 1.1596x over previous
//
#include <hip/hip_runtime.h>
#include <hip/hip_bf16.h>
#include <hip/hip_fp16.h>

typedef unsigned short u16;
typedef __attribute__((ext_vector_type(8))) short short8;
typedef __attribute__((ext_vector_type(8))) u16 u16x8;
typedef __attribute__((ext_vector_type(4))) u16 u16x4;
typedef __attribute__((ext_vector_type(8))) _Float16 half8;
typedef __attribute__((ext_vector_type(4))) float f32x4;

#define NB 8
#define TQn 1024
#define TKn 4096
#define DINn 1024
#define DOUTn 256
#define NROWS (NB * TQn)
#define NKB (TKn / 128)
#define EXPSHIFT 40.0f
#define LP 40   // LDS row stride (u16) = 80 B: 16B-aligned rows, b128-conflict-free

#define DEV static __device__ __forceinline__

DEV u16 f2bf(float x) {
    __hip_bfloat16 h = __float2bfloat16(x);
    return *reinterpret_cast<u16*>(&h);
}
DEV float bf2f(u16 u) {
    __hip_bfloat16 h;
    *reinterpret_cast<u16*>(&h) = u;
    return __bfloat162float(h);
}
DEV void split2(float x, u16& hi, u16& lo) {
    u16 h = f2bf(x);
    float hf = bf2f(h);
    hi = h;
    lo = f2bf(x - hf);
}
DEV void split4(const float4 v, u16x4& h, u16x4& l) {
    u16 h0, l0, h1, l1, h2, l2, h3, l3;
    split2(v.x, h0, l0);
    split2(v.y, h1, l1);
    split2(v.z, h2, l2);
    split2(v.w, h3, l3);
    h = (u16x4){h0, h1, h2, h3};
    l = (u16x4){l0, l1, l2, l3};
}
// 16B-aligned LDS accesses (callers guarantee 16B alignment with LP=40)
DEV short8 ld8s(const u16* p) { return *reinterpret_cast<const short8*>(p); }
DEV half8 ld8h(const u16* p) { return *reinterpret_cast<const half8*>(p); }
DEV void st8(u16* p, u16x8 v) { *reinterpret_cast<u16x8*>(p) = v; }

// ---------------------------------------------------------------------------
// Kernel 1: transpose+convert emb [B][TK][DOUT] fp32 -> embT [B][DOUT][TK] fp16
// ---------------------------------------------------------------------------
__global__ __launch_bounds__(256) void k_embT(const float* __restrict__ emb,
                                              _Float16* __restrict__ embT) {
    __shared__ float tile[64][65];
    const int b = blockIdx.z;
    const int k0 = blockIdx.x * 64;
    const int o0 = blockIdx.y * 64;
    const int t = threadIdx.x;
    const int c = t & 63;
    const int r0 = t >> 6;
#pragma unroll
    for (int i = 0; i < 16; i++) {
        int r = r0 + i * 4;
        tile[c][r] = emb[((size_t)b * TKn + k0 + r) * DOUTn + o0 + c];
    }
    __syncthreads();
#pragma unroll
    for (int i = 0; i < 16; i++) {
        int r = r0 + i * 4;
        embT[((size_t)b * DOUTn + o0 + r) * TKn + k0 + c] = (_Float16)tile[r][c];
    }
}

// ---------------------------------------------------------------------------
// Kernel 2: linear  decsmall = dec @ W^T + b, split into hi/lo bf16
// ---------------------------------------------------------------------------
__global__ __launch_bounds__(256) void k_linear(const float* __restrict__ dec,
                                                const float* __restrict__ W,
                                                const float* __restrict__ bias,
                                                u16* __restrict__ ds_hi,
                                                u16* __restrict__ ds_lo) {
    __shared__ u16 sAh[128][LP], sAl[128][LP], sBh[64][LP], sBl[64][LP];
    const int t = threadIdx.x;
    const int m0 = blockIdx.x * 128;
    const int n0 = blockIdx.y * 64;
    const int w = t >> 6, lane = t & 63;
    const int wr = w >> 1, wc = w & 1;
    const int lr = lane & 15, g = lane >> 4, kg8 = g * 8;

    f32x4 acc[4][2];
#pragma unroll
    for (int m = 0; m < 4; m++)
#pragma unroll
        for (int n = 0; n < 2; n++) acc[m][n] = (f32x4){0.f, 0.f, 0.f, 0.f};

    for (int k0 = 0; k0 < DINn; k0 += 32) {
        __syncthreads();
#pragma unroll
        for (int i = 0; i < 4; i++) {
            int f = i * 256 + t;
            int row = f >> 3, c4 = (f & 7) * 4;
            const float4 v = *reinterpret_cast<const float4*>(
                dec + (size_t)(m0 + row) * DINn + k0 + c4);
            u16x4 h, l;
            split4(v, h, l);
            *reinterpret_cast<u16x4*>(&sAh[row][c4]) = h;
            *reinterpret_cast<u16x4*>(&sAl[row][c4]) = l;
        }
#pragma unroll
        for (int i = 0; i < 2; i++) {
            int f = i * 256 + t;
            int row = f >> 3, c4 = (f & 7) * 4;
            const float4 v = *reinterpret_cast<const float4*>(
                W + (size_t)(n0 + row) * DINn + k0 + c4);
            u16x4 h, l;
            split4(v, h, l);
            *reinterpret_cast<u16x4*>(&sBh[row][c4]) = h;
            *reinterpret_cast<u16x4*>(&sBl[row][c4]) = l;
        }
        __syncthreads();
        short8 ah[4], al[4], bh[2], bl[2];
#pragma unroll
        for (int m = 0; m < 4; m++) {
            int row = wr * 64 + m * 16 + lr;
            ah[m] = ld8s(&sAh[row][kg8]);
            al[m] = ld8s(&sAl[row][kg8]);
        }
#pragma unroll
        for (int n = 0; n < 2; n++) {
            int row = wc * 32 + n * 16 + lr;
            bh[n] = ld8s(&sBh[row][kg8]);
            bl[n] = ld8s(&sBl[row][kg8]);
        }
#pragma unroll
        for (int m = 0; m < 4; m++)
#pragma unroll
            for (int n = 0; n < 2; n++) {
                acc[m][n] = __builtin_amdgcn_mfma_f32_16x16x32_bf16(ah[m], bh[n], acc[m][n], 0, 0, 0);
                acc[m][n] = __builtin_amdgcn_mfma_f32_16x16x32_bf16(ah[m], bl[n], acc[m][n], 0, 0, 0);
                acc[m][n] = __builtin_amdgcn_mfma_f32_16x16x32_bf16(al[m], bh[n], acc[m][n], 0, 0, 0);
            }
    }
#pragma unroll
    for (int m = 0; m < 4; m++) {
#pragma unroll
        for (int n = 0; n < 2; n++) {
            int colg = n0 + wc * 32 + n * 16 + lr;
            float bv = bias[colg];
#pragma unroll
            for (int r = 0; r < 4; r++) {
                int rowg = m0 + wr * 64 + m * 16 + g * 4 + r;
                float v = acc[m][n][r] + bv;
                u16 h, l;
                split2(v, h, l);
                ds_hi[(size_t)rowg * DOUTn + colg] = h;
                ds_lo[(size_t)rowg * DOUTn + colg] = l;
            }
        }
    }
}

// ---------------------------------------------------------------------------
// Kernel 3: scores GEMM (split 3-MFMA) + mask + p_u = exp(s - 40) nt-write
//           + per-row partial sums -> partsum[kb][row]
// ---------------------------------------------------------------------------
__global__ __launch_bounds__(256) void k_scores_exp(const u16* __restrict__ ds_hi,
                                                    const u16* __restrict__ ds_lo,
                                                    const float* __restrict__ emb,
                                                    const int* __restrict__ emask,
                                                    float* __restrict__ attn,
                                                    float* __restrict__ partsum) {
    __shared__ u16 sAh[128][LP], sAl[128][LP], sBh[128][LP], sBl[128][LP];
    __shared__ float sSum[2][128];
    const int t = threadIdx.x;
    const int flat = blockIdx.x + 8 * (blockIdx.y + 32 * blockIdx.z);
    const int b = flat & 7;
    const int rest = flat >> 3;
    const int kb = rest & 31;
    const int q0 = (rest >> 5) * 128;
    const int kb0 = kb * 128;
    const int w = t >> 6, lane = t & 63;
    const int wr = w >> 1, wc = w & 1;
    const int lr = lane & 15, g = lane >> 4, kg8 = g * 8;

    f32x4 acc[4][4];
#pragma unroll
    for (int m = 0; m < 4; m++)
#pragma unroll
        for (int n = 0; n < 4; n++) acc[m][n] = (f32x4){0.f, 0.f, 0.f, 0.f};

    for (int o0 = 0; o0 < DOUTn; o0 += 32) {
        __syncthreads();
#pragma unroll
        for (int i = 0; i < 2; i++) {
            int f8 = i * 256 + t;
            int row = f8 >> 2, c8 = (f8 & 3) * 8;
            size_t src = (size_t)(b * TQn + q0 + row) * DOUTn + o0 + c8;
            st8(&sAh[row][c8], *reinterpret_cast<const u16x8*>(ds_hi + src));
            st8(&sAl[row][c8], *reinterpret_cast<const u16x8*>(ds_lo + src));
        }
#pragma unroll
        for (int i = 0; i < 4; i++) {
            int f = i * 256 + t;
            int row = f >> 3, c4 = (f & 7) * 4;
            const float4 v = *reinterpret_cast<const float4*>(
                emb + (size_t)(b * TKn + kb0 + row) * DOUTn + o0 + c4);
            u16x4 h, l;
            split4(v, h, l);
            *reinterpret_cast<u16x4*>(&sBh[row][c4]) = h;
            *reinterpret_cast<u16x4*>(&sBl[row][c4]) = l;
        }
        __syncthreads();
        short8 ah[4], al[4], bh[4], bl[4];
#pragma unroll
        for (int m = 0; m < 4; m++) {
            int row = wr * 64 + m * 16 + lr;
            ah[m] = ld8s(&sAh[row][kg8]);
            al[m] = ld8s(&sAl[row][kg8]);
        }
#pragma unroll
        for (int n = 0; n < 4; n++) {
            int row = wc * 64 + n * 16 + lr;
            bh[n] = ld8s(&sBh[row][kg8]);
            bl[n] = ld8s(&sBl[row][kg8]);
        }
#pragma unroll
        for (int m = 0; m < 4; m++)
#pragma unroll
            for (int n = 0; n < 4; n++) {
                acc[m][n] = __builtin_amdgcn_mfma_f32_16x16x32_bf16(ah[m], bh[n], acc[m][n], 0, 0, 0);
                acc[m][n] = __builtin_amdgcn_mfma_f32_16x16x32_bf16(ah[m], bl[n], acc[m][n], 0, 0, 0);
                acc[m][n] = __builtin_amdgcn_mfma_f32_16x16x32_bf16(al[m], bh[n], acc[m][n], 0, 0, 0);
            }
    }
    const int* em = emask + (size_t)b * TKn;
    float* pout = attn + ((size_t)(b * TQn + q0)) * TKn + kb0;
    float rowAcc[4][4];
#pragma unroll
    for (int m = 0; m < 4; m++)
#pragma unroll
        for (int r = 0; r < 4; r++) rowAcc[m][r] = 0.f;

#pragma unroll
    for (int n = 0; n < 4; n++) {
        int colL = wc * 64 + n * 16 + lr;
        int mk = em[kb0 + colL];
#pragma unroll
        for (int m = 0; m < 4; m++) {
#pragma unroll
            for (int r = 0; r < 4; r++) {
                int rowL = wr * 64 + m * 16 + g * 4 + r;
                float p = mk ? __expf(acc[m][n][r] - EXPSHIFT) : 0.f;
                __builtin_nontemporal_store(p, &pout[(size_t)rowL * TKn + colL]);
                rowAcc[m][r] += p;
            }
        }
    }
#pragma unroll
    for (int m = 0; m < 4; m++) {
#pragma unroll
        for (int r = 0; r < 4; r++) {
            float v = rowAcc[m][r];
            v += __shfl_xor(v, 1);
            v += __shfl_xor(v, 2);
            v += __shfl_xor(v, 4);
            v += __shfl_xor(v, 8);
            if (lr == 0) sSum[wc][wr * 64 + m * 16 + g * 4 + r] = v;
        }
    }
    __syncthreads();
    if (t < 128) {
        partsum[(size_t)kb * NROWS + (size_t)b * TQn + q0 + t] =
            sSum[0][t] + sSum[1][t];
    }
}

// ---------------------------------------------------------------------------
// Kernel 4: inv_sum[row] = 1 / sum_kb partsum[kb][row]
// ---------------------------------------------------------------------------
__global__ __launch_bounds__(256) void k_rowsum(const float* __restrict__ partsum,
                                                float* __restrict__ inv_sum) {
    int row = blockIdx.x * 256 + threadIdx.x;
    float s = 0.f;
#pragma unroll
    for (int kb = 0; kb < NKB; kb++) s += partsum[(size_t)kb * NROWS + row];
    inv_sum[row] = 1.0f / s;
}

// ---------------------------------------------------------------------------
// Kernel 5: PV GEMM + attn normalize write-back. 2-phase, 1 barrier/iter,
// double-buffered LDS, reg-staged prefetch issued a full compute-phase ahead.
// Block: 64 q x 256 o x K-chunk 1024 (split-K x4), 256 thr (4 waves; wave w
// owns cols w*64.., all 64 rows: 16 MFMA/iter). KT=32.
// A-transform: v = p_u * inv; PLAIN store back to attn (final attn value);
// cvt fp16 -> LDS. Writes partial[kc] in epilogue. XCD decode flat%8 = b.
// ---------------------------------------------------------------------------
__global__ __launch_bounds__(256) void k_pv6(float* __restrict__ attn,
                                             const _Float16* __restrict__ embT,
                                             const float* __restrict__ inv_sum,
                                             float* __restrict__ partial) {
    __shared__ u16 sA[2][64][LP];    // fp16 bits, 64 q x 32 k
    __shared__ u16 sB[2][256][LP];   // fp16 bits, 256 o x 32 k
    __shared__ float sInv[64];
    const int t = threadIdx.x;
    const int flat = blockIdx.x;  // 0..511
    const int b = flat & 7;
    const int rest = flat >> 3;
    const int kc = rest & 3;
    const int q0 = (rest >> 2) * 64;
    const int w = t >> 6, lane = t & 63;
    const int lr = lane & 15, g = lane >> 4, kg8 = g * 8;
    const int kbase = kc * 1024;
    const size_t rowBase = (size_t)b * TQn + q0;
    const u16* ebt = reinterpret_cast<const u16*>(embT);

    if (t < 64) sInv[t] = inv_sum[rowBase + t];

    // staging assignments
    // A: 64 rows x 32 k fp32 = 2048 f32 / 256 thr = 2 x f32x4 per thread
    const int ar0 = t >> 3, ac4 = (t & 7) * 4;         // i=0: rows 0..31
    // B: 256 rows x 32 k u16 = 8192 u16 / 256 thr = 4 x u16x8 per thread
    //    i-th: row = (i*256+t)>>2, c8 = ((i*256+t)&3)*8

    f32x4 acc[4][4];
#pragma unroll
    for (int m = 0; m < 4; m++)
#pragma unroll
        for (int n = 0; n < 4; n++) acc[m][n] = (f32x4){0.f, 0.f, 0.f, 0.f};

    // prologue: prefetch tile 0
    f32x4 pa[2];
    u16x8 pb[4];
#pragma unroll
    for (int i = 0; i < 2; i++) {
        int row = ar0 + i * 32;
        pa[i] = *reinterpret_cast<const f32x4*>(attn + (rowBase + row) * TKn + kbase + ac4);
    }
#pragma unroll
    for (int i = 0; i < 4; i++) {
        int f = i * 256 + t;
        int row = f >> 2, c8 = (f & 3) * 8;
        pb[i] = *reinterpret_cast<const u16x8*>(
            ebt + (size_t)(b * DOUTn + row) * TKn + kbase + c8);
    }
    __syncthreads();  // sInv ready

    const int NIT = 1024 / 32;
    for (int it = 0; it < NIT; it++) {
        const int cur = it & 1;
        const int ks = it * 32;
        // commit tile it: A transform (scale, write-back attn, cvt) + B
#pragma unroll
        for (int i = 0; i < 2; i++) {
            int row = ar0 + i * 32;
            f32x4 v = pa[i] * sInv[row];
            *reinterpret_cast<f32x4*>(attn + (rowBase + row) * TKn + kbase + ks + ac4) = v;
            u16x4 hv;
            hv[0] = __builtin_bit_cast(u16, (_Float16)v[0]);
            hv[1] = __builtin_bit_cast(u16, (_Float16)v[1]);
            hv[2] = __builtin_bit_cast(u16, (_Float16)v[2]);
            hv[3] = __builtin_bit_cast(u16, (_Float16)v[3]);
            *reinterpret_cast<u16x4*>(&sA[cur][row][ac4]) = hv;
        }
#pragma unroll
        for (int i = 0; i < 4; i++) {
            int f = i * 256 + t;
            int row = f >> 2, c8 = (f & 3) * 8;
            st8(&sB[cur][row][c8], pb[i]);
        }
        __syncthreads();  // buf[cur] ready (single barrier per iter)
        // prefetch tile it+1 into regs (in flight during compute below)
        if (it + 1 < NIT) {
            int ksn = ks + 32;
#pragma unroll
            for (int i = 0; i < 2; i++) {
                int row = ar0 + i * 32;
                pa[i] = *reinterpret_cast<const f32x4*>(
                    attn + (rowBase + row) * TKn + kbase + ksn + ac4);
            }
#pragma unroll
            for (int i = 0; i < 4; i++) {
                int f = i * 256 + t;
                int row = f >> 2, c8 = (f & 3) * 8;
                pb[i] = *reinterpret_cast<const u16x8*>(
                    ebt + (size_t)(b * DOUTn + row) * TKn + kbase + ksn + c8);
            }
        }
        // compute tile it: 16 MFMA per wave
        half8 a[4], bb[4];
#pragma unroll
        for (int m = 0; m < 4; m++) a[m] = ld8h(&sA[cur][m * 16 + lr][kg8]);
#pragma unroll
        for (int n = 0; n < 4; n++) bb[n] = ld8h(&sB[cur][w * 64 + n * 16 + lr][kg8]);
#pragma unroll
        for (int m = 0; m < 4; m++)
#pragma unroll
            for (int n = 0; n < 4; n++)
                acc[m][n] = __builtin_amdgcn_mfma_f32_16x16x32_f16(a[m], bb[n], acc[m][n], 0, 0, 0);
    }
    // epilogue: partial[kc][row][col]
#pragma unroll
    for (int m = 0; m < 4; m++) {
#pragma unroll
        for (int n = 0; n < 4; n++) {
            int col = w * 64 + n * 16 + lr;
#pragma unroll
            for (int r = 0; r < 4; r++) {
                size_t grow = rowBase + m * 16 + g * 4 + r;
                partial[((size_t)kc * NROWS + grow) * DOUTn + col] = acc[m][n][r];
            }
        }
    }
}

// ---------------------------------------------------------------------------
// Kernel 6: out = sum of 4 partials
// ---------------------------------------------------------------------------
__global__ __launch_bounds__(256) void k_reduce(const float* __restrict__ partial,
                                                float* __restrict__ out) {
    const size_t stride = (size_t)NROWS * DOUTn;
    size_t i = ((size_t)blockIdx.x * 256 + threadIdx.x) * 4;
    f32x4 a0 = *reinterpret_cast<const f32x4*>(partial + i);
    f32x4 a1 = *reinterpret_cast<const f32x4*>(partial + stride + i);
    f32x4 a2 = *reinterpret_cast<const f32x4*>(partial + 2 * stride + i);
    f32x4 a3 = *reinterpret_cast<const f32x4*>(partial + 3 * stride + i);
    f32x4 s = (a0 + a1) + (a2 + a3);
    *reinterpret_cast<f32x4*>(out + i) = s;
}

// ---------------------------------------------------------------------------
extern "C" void kernel_launch(void* const* d_in, const int* in_sizes, int n_in,
                              void* d_out, int out_size, void* d_ws, size_t ws_size,
                              hipStream_t stream) {
    const float* dec = (const float*)d_in[0];
    const float* emb = (const float*)d_in[1];
    const int* emask = (const int*)d_in[2];
    const float* W = (const float*)d_in[3];
    const float* bias = (const float*)d_in[4];

    float* out = (float*)d_out;
    float* attn = out + (size_t)NROWS * DOUTn;

    char* wsb = (char*)d_ws;
    u16* ds_hi = (u16*)wsb;
    wsb += (size_t)NROWS * DOUTn * 2;
    u16* ds_lo = (u16*)wsb;
    wsb += (size_t)NROWS * DOUTn * 2;
    _Float16* embT = (_Float16*)wsb;
    wsb += (size_t)NB * DOUTn * TKn * 2;
    float* inv_sum = (float*)wsb;
    wsb += (size_t)NROWS * 4;
    float* partsum = (float*)wsb;
    wsb += (size_t)NKB * NROWS * 4;
    float* partial = (float*)wsb;  // 4 * 8192 * 256 fp32 = 33.5 MB

    k_embT<<<dim3(TKn / 64, DOUTn / 64, NB), 256, 0, stream>>>(emb, embT);
    k_linear<<<dim3(NROWS / 128, DOUTn / 64), 256, 0, stream>>>(dec, W, bias, ds_hi, ds_lo);
    k_scores_exp<<<dim3(TQn / 128, NKB, NB), 256, 0, stream>>>(ds_hi, ds_lo, emb, emask, attn, partsum);
    k_rowsum<<<dim3(NROWS / 256), 256, 0, stream>>>(partsum, inv_sum);
    k_pv6<<<dim3(512), 256, 0, stream>>>(attn, embT, inv_sum, partial);
    k_reduce<<<dim3((NROWS * DOUTn / 4) / 256), 256, 0, stream>>>(partial, out);
}

// Round 9
// 229.399 us; speedup vs baseline: 1.4820x; 1.0120x over previous
//
#include <hip/hip_runtime.h>
#include <hip/hip_bf16.h>
#include <hip/hip_fp16.h>

typedef unsigned short u16;
typedef __attribute__((ext_vector_type(8))) short short8;
typedef __attribute__((ext_vector_type(8))) u16 u16x8;
typedef __attribute__((ext_vector_type(4))) u16 u16x4;
typedef __attribute__((ext_vector_type(8))) _Float16 half8;
typedef __attribute__((ext_vector_type(4))) float f32x4;

#define NB 8
#define TQn 1024
#define TKn 4096
#define DINn 1024
#define DOUTn 256
#define NROWS (NB * TQn)
#define NKB (TKn / 128)
#define EXPSHIFT 40.0f
#define LP 40   // LDS row stride (u16) = 80 B: 16B-aligned rows

#define DEV static __device__ __forceinline__

DEV u16 f2bf(float x) {
    __hip_bfloat16 h = __float2bfloat16(x);
    return *reinterpret_cast<u16*>(&h);
}
DEV float bf2f(u16 u) {
    __hip_bfloat16 h;
    *reinterpret_cast<u16*>(&h) = u;
    return __bfloat162float(h);
}
DEV void split2(float x, u16& hi, u16& lo) {
    u16 h = f2bf(x);
    float hf = bf2f(h);
    hi = h;
    lo = f2bf(x - hf);
}
DEV void split4(const float4 v, u16x4& h, u16x4& l) {
    u16 h0, l0, h1, l1, h2, l2, h3, l3;
    split2(v.x, h0, l0);
    split2(v.y, h1, l1);
    split2(v.z, h2, l2);
    split2(v.w, h3, l3);
    h = (u16x4){h0, h1, h2, h3};
    l = (u16x4){l0, l1, l2, l3};
}
DEV short8 ld8s(const u16* p) { return *reinterpret_cast<const short8*>(p); }
DEV half8 ld8h(const u16* p) { return *reinterpret_cast<const half8*>(p); }
DEV void st8(u16* p, u16x8 v) { *reinterpret_cast<u16x8*>(p) = v; }

// ---------------------------------------------------------------------------
// Kernel 1: transpose+convert emb [B][TK][DOUT] fp32 -> embT [B][DOUT][TK] fp16
// ---------------------------------------------------------------------------
__global__ __launch_bounds__(256) void k_embT(const float* __restrict__ emb,
                                              _Float16* __restrict__ embT) {
    __shared__ float tile[64][65];
    const int b = blockIdx.z;
    const int k0 = blockIdx.x * 64;
    const int o0 = blockIdx.y * 64;
    const int t = threadIdx.x;
    const int c = t & 63;
    const int r0 = t >> 6;
#pragma unroll
    for (int i = 0; i < 16; i++) {
        int r = r0 + i * 4;
        tile[c][r] = emb[((size_t)b * TKn + k0 + r) * DOUTn + o0 + c];
    }
    __syncthreads();
#pragma unroll
    for (int i = 0; i < 16; i++) {
        int r = r0 + i * 4;
        embT[((size_t)b * DOUTn + o0 + r) * TKn + k0 + c] = (_Float16)tile[r][c];
    }
}

// ---------------------------------------------------------------------------
// Kernel 2: linear  decsmall = dec @ W^T + b, split into hi/lo bf16
// ---------------------------------------------------------------------------
__global__ __launch_bounds__(256) void k_linear(const float* __restrict__ dec,
                                                const float* __restrict__ W,
                                                const float* __restrict__ bias,
                                                u16* __restrict__ ds_hi,
                                                u16* __restrict__ ds_lo) {
    __shared__ u16 sAh[128][LP], sAl[128][LP], sBh[64][LP], sBl[64][LP];
    const int t = threadIdx.x;
    const int m0 = blockIdx.x * 128;
    const int n0 = blockIdx.y * 64;
    const int w = t >> 6, lane = t & 63;
    const int wr = w >> 1, wc = w & 1;
    const int lr = lane & 15, g = lane >> 4, kg8 = g * 8;

    f32x4 acc[4][2];
#pragma unroll
    for (int m = 0; m < 4; m++)
#pragma unroll
        for (int n = 0; n < 2; n++) acc[m][n] = (f32x4){0.f, 0.f, 0.f, 0.f};

    for (int k0 = 0; k0 < DINn; k0 += 32) {
        __syncthreads();
#pragma unroll
        for (int i = 0; i < 4; i++) {
            int f = i * 256 + t;
            int row = f >> 3, c4 = (f & 7) * 4;
            const float4 v = *reinterpret_cast<const float4*>(
                dec + (size_t)(m0 + row) * DINn + k0 + c4);
            u16x4 h, l;
            split4(v, h, l);
            *reinterpret_cast<u16x4*>(&sAh[row][c4]) = h;
            *reinterpret_cast<u16x4*>(&sAl[row][c4]) = l;
        }
#pragma unroll
        for (int i = 0; i < 2; i++) {
            int f = i * 256 + t;
            int row = f >> 3, c4 = (f & 7) * 4;
            const float4 v = *reinterpret_cast<const float4*>(
                W + (size_t)(n0 + row) * DINn + k0 + c4);
            u16x4 h, l;
            split4(v, h, l);
            *reinterpret_cast<u16x4*>(&sBh[row][c4]) = h;
            *reinterpret_cast<u16x4*>(&sBl[row][c4]) = l;
        }
        __syncthreads();
        short8 ah[4], al[4], bh[2], bl[2];
#pragma unroll
        for (int m = 0; m < 4; m++) {
            int row = wr * 64 + m * 16 + lr;
            ah[m] = ld8s(&sAh[row][kg8]);
            al[m] = ld8s(&sAl[row][kg8]);
        }
#pragma unroll
        for (int n = 0; n < 2; n++) {
            int row = wc * 32 + n * 16 + lr;
            bh[n] = ld8s(&sBh[row][kg8]);
            bl[n] = ld8s(&sBl[row][kg8]);
        }
#pragma unroll
        for (int m = 0; m < 4; m++)
#pragma unroll
            for (int n = 0; n < 2; n++) {
                acc[m][n] = __builtin_amdgcn_mfma_f32_16x16x32_bf16(ah[m], bh[n], acc[m][n], 0, 0, 0);
                acc[m][n] = __builtin_amdgcn_mfma_f32_16x16x32_bf16(ah[m], bl[n], acc[m][n], 0, 0, 0);
                acc[m][n] = __builtin_amdgcn_mfma_f32_16x16x32_bf16(al[m], bh[n], acc[m][n], 0, 0, 0);
            }
    }
#pragma unroll
    for (int m = 0; m < 4; m++) {
#pragma unroll
        for (int n = 0; n < 2; n++) {
            int colg = n0 + wc * 32 + n * 16 + lr;
            float bv = bias[colg];
#pragma unroll
            for (int r = 0; r < 4; r++) {
                int rowg = m0 + wr * 64 + m * 16 + g * 4 + r;
                float v = acc[m][n][r] + bv;
                u16 h, l;
                split2(v, h, l);
                ds_hi[(size_t)rowg * DOUTn + colg] = h;
                ds_lo[(size_t)rowg * DOUTn + colg] = l;
            }
        }
    }
}

// ---------------------------------------------------------------------------
// Kernel 3: scores GEMM (split 3-MFMA) + mask + p_u = exp(s - 40) nt-write
//           + per-row partial sums -> partsum[kb][row]
// ---------------------------------------------------------------------------
__global__ __launch_bounds__(256) void k_scores_exp(const u16* __restrict__ ds_hi,
                                                    const u16* __restrict__ ds_lo,
                                                    const float* __restrict__ emb,
                                                    const int* __restrict__ emask,
                                                    float* __restrict__ attn,
                                                    float* __restrict__ partsum) {
    __shared__ u16 sAh[128][LP], sAl[128][LP], sBh[128][LP], sBl[128][LP];
    __shared__ float sSum[2][128];
    const int t = threadIdx.x;
    const int flat = blockIdx.x + 8 * (blockIdx.y + 32 * blockIdx.z);
    const int b = flat & 7;
    const int rest = flat >> 3;
    const int kb = rest & 31;
    const int q0 = (rest >> 5) * 128;
    const int kb0 = kb * 128;
    const int w = t >> 6, lane = t & 63;
    const int wr = w >> 1, wc = w & 1;
    const int lr = lane & 15, g = lane >> 4, kg8 = g * 8;

    f32x4 acc[4][4];
#pragma unroll
    for (int m = 0; m < 4; m++)
#pragma unroll
        for (int n = 0; n < 4; n++) acc[m][n] = (f32x4){0.f, 0.f, 0.f, 0.f};

    for (int o0 = 0; o0 < DOUTn; o0 += 32) {
        __syncthreads();
#pragma unroll
        for (int i = 0; i < 2; i++) {
            int f8 = i * 256 + t;
            int row = f8 >> 2, c8 = (f8 & 3) * 8;
            size_t src = (size_t)(b * TQn + q0 + row) * DOUTn + o0 + c8;
            st8(&sAh[row][c8], *reinterpret_cast<const u16x8*>(ds_hi + src));
            st8(&sAl[row][c8], *reinterpret_cast<const u16x8*>(ds_lo + src));
        }
#pragma unroll
        for (int i = 0; i < 4; i++) {
            int f = i * 256 + t;
            int row = f >> 3, c4 = (f & 7) * 4;
            const float4 v = *reinterpret_cast<const float4*>(
                emb + (size_t)(b * TKn + kb0 + row) * DOUTn + o0 + c4);
            u16x4 h, l;
            split4(v, h, l);
            *reinterpret_cast<u16x4*>(&sBh[row][c4]) = h;
            *reinterpret_cast<u16x4*>(&sBl[row][c4]) = l;
        }
        __syncthreads();
        short8 ah[4], al[4], bh[4], bl[4];
#pragma unroll
        for (int m = 0; m < 4; m++) {
            int row = wr * 64 + m * 16 + lr;
            ah[m] = ld8s(&sAh[row][kg8]);
            al[m] = ld8s(&sAl[row][kg8]);
        }
#pragma unroll
        for (int n = 0; n < 4; n++) {
            int row = wc * 64 + n * 16 + lr;
            bh[n] = ld8s(&sBh[row][kg8]);
            bl[n] = ld8s(&sBl[row][kg8]);
        }
#pragma unroll
        for (int m = 0; m < 4; m++)
#pragma unroll
            for (int n = 0; n < 4; n++) {
                acc[m][n] = __builtin_amdgcn_mfma_f32_16x16x32_bf16(ah[m], bh[n], acc[m][n], 0, 0, 0);
                acc[m][n] = __builtin_amdgcn_mfma_f32_16x16x32_bf16(ah[m], bl[n], acc[m][n], 0, 0, 0);
                acc[m][n] = __builtin_amdgcn_mfma_f32_16x16x32_bf16(al[m], bh[n], acc[m][n], 0, 0, 0);
            }
    }
    const int* em = emask + (size_t)b * TKn;
    float* pout = attn + ((size_t)(b * TQn + q0)) * TKn + kb0;
    float rowAcc[4][4];
#pragma unroll
    for (int m = 0; m < 4; m++)
#pragma unroll
        for (int r = 0; r < 4; r++) rowAcc[m][r] = 0.f;

#pragma unroll
    for (int n = 0; n < 4; n++) {
        int colL = wc * 64 + n * 16 + lr;
        int mk = em[kb0 + colL];
#pragma unroll
        for (int m = 0; m < 4; m++) {
#pragma unroll
            for (int r = 0; r < 4; r++) {
                int rowL = wr * 64 + m * 16 + g * 4 + r;
                float p = mk ? __expf(acc[m][n][r] - EXPSHIFT) : 0.f;
                __builtin_nontemporal_store(p, &pout[(size_t)rowL * TKn + colL]);
                rowAcc[m][r] += p;
            }
        }
    }
#pragma unroll
    for (int m = 0; m < 4; m++) {
#pragma unroll
        for (int r = 0; r < 4; r++) {
            float v = rowAcc[m][r];
            v += __shfl_xor(v, 1);
            v += __shfl_xor(v, 2);
            v += __shfl_xor(v, 4);
            v += __shfl_xor(v, 8);
            if (lr == 0) sSum[wc][wr * 64 + m * 16 + g * 4 + r] = v;
        }
    }
    __syncthreads();
    if (t < 128) {
        partsum[(size_t)kb * NROWS + (size_t)b * TQn + q0 + t] =
            sSum[0][t] + sSum[1][t];
    }
}

// ---------------------------------------------------------------------------
// Kernel 4: inv_sum[row] = 1 / sum_kb partsum[kb][row]
// ---------------------------------------------------------------------------
__global__ __launch_bounds__(256) void k_rowsum(const float* __restrict__ partsum,
                                                float* __restrict__ inv_sum) {
    int row = blockIdx.x * 256 + threadIdx.x;
    float s = 0.f;
#pragma unroll
    for (int kb = 0; kb < NKB; kb++) s += partsum[(size_t)kb * NROWS + row];
    inv_sum[row] = 1.0f / s;
}

// ---------------------------------------------------------------------------
// Kernel 5: PV GEMM + attn normalize write-back. Same tiling as pv6
// (64q x 256o x K-chunk 1024, split-K x4, KT=32, dbuf LDS, 4 waves) but the
// per-iter __syncthreads is replaced with lgkmcnt(0) + RAW s_barrier:
// no vmcnt(0) drain -> prefetch loads and attn write-back stores stay in
// flight across the barrier. Loop: commit(it) -> barrier -> prefetch(it+1)
// -> compute(it).
// ---------------------------------------------------------------------------
__global__ __launch_bounds__(256) void k_pv7(float* __restrict__ attn,
                                             const _Float16* __restrict__ embT,
                                             const float* __restrict__ inv_sum,
                                             float* __restrict__ partial) {
    __shared__ u16 sA[2][64][LP];    // fp16 bits, 64 q x 32 k
    __shared__ u16 sB[2][256][LP];   // fp16 bits, 256 o x 32 k
    __shared__ float sInv[64];
    const int t = threadIdx.x;
    const int flat = blockIdx.x;  // 0..511
    const int b = flat & 7;
    const int rest = flat >> 3;
    const int kc = rest & 3;
    const int q0 = (rest >> 2) * 64;
    const int w = t >> 6, lane = t & 63;
    const int lr = lane & 15, g = lane >> 4, kg8 = g * 8;
    const int kbase = kc * 1024;
    const size_t rowBase = (size_t)b * TQn + q0;
    const u16* ebt = reinterpret_cast<const u16*>(embT);

    if (t < 64) sInv[t] = inv_sum[rowBase + t];

    const int ar0 = t >> 3, ac4 = (t & 7) * 4;

    f32x4 acc[4][4];
#pragma unroll
    for (int m = 0; m < 4; m++)
#pragma unroll
        for (int n = 0; n < 4; n++) acc[m][n] = (f32x4){0.f, 0.f, 0.f, 0.f};

    // prologue: prefetch tile 0
    f32x4 pa[2];
    u16x8 pb[4];
#pragma unroll
    for (int i = 0; i < 2; i++) {
        int row = ar0 + i * 32;
        pa[i] = *reinterpret_cast<const f32x4*>(attn + (rowBase + row) * TKn + kbase + ac4);
    }
#pragma unroll
    for (int i = 0; i < 4; i++) {
        int f = i * 256 + t;
        int row = f >> 2, c8 = (f & 3) * 8;
        pb[i] = *reinterpret_cast<const u16x8*>(
            ebt + (size_t)(b * DOUTn + row) * TKn + kbase + c8);
    }
    __syncthreads();  // sInv ready (full barrier once)

    const int NIT = 1024 / 32;
    for (int it = 0; it < NIT; it++) {
        const int cur = it & 1;
        const int ks = it * 32;
        // ---- commit tile it into buf[cur] ----
#pragma unroll
        for (int i = 0; i < 2; i++) {
            int row = ar0 + i * 32;
            f32x4 v = pa[i] * sInv[row];
            *reinterpret_cast<f32x4*>(attn + (rowBase + row) * TKn + kbase + ks + ac4) = v;
            u16x4 hv;
            hv[0] = __builtin_bit_cast(u16, (_Float16)v[0]);
            hv[1] = __builtin_bit_cast(u16, (_Float16)v[1]);
            hv[2] = __builtin_bit_cast(u16, (_Float16)v[2]);
            hv[3] = __builtin_bit_cast(u16, (_Float16)v[3]);
            *reinterpret_cast<u16x4*>(&sA[cur][row][ac4]) = hv;
        }
#pragma unroll
        for (int i = 0; i < 4; i++) {
            int f = i * 256 + t;
            int row = f >> 2, c8 = (f & 3) * 8;
            st8(&sB[cur][row][c8], pb[i]);
        }
        // ---- raw barrier: LDS visibility only, NO vmcnt drain ----
        asm volatile("s_waitcnt lgkmcnt(0)" ::: "memory");
        __builtin_amdgcn_s_barrier();
        asm volatile("" ::: "memory");
        // ---- prefetch tile it+1 (stays in flight through compute) ----
        if (it + 1 < NIT) {
            int ksn = ks + 32;
#pragma unroll
            for (int i = 0; i < 2; i++) {
                int row = ar0 + i * 32;
                pa[i] = *reinterpret_cast<const f32x4*>(
                    attn + (rowBase + row) * TKn + kbase + ksn + ac4);
            }
#pragma unroll
            for (int i = 0; i < 4; i++) {
                int f = i * 256 + t;
                int row = f >> 2, c8 = (f & 3) * 8;
                pb[i] = *reinterpret_cast<const u16x8*>(
                    ebt + (size_t)(b * DOUTn + row) * TKn + kbase + ksn + c8);
            }
        }
        // ---- compute tile it: 16 MFMA per wave ----
        half8 a[4], bb[4];
#pragma unroll
        for (int m = 0; m < 4; m++) a[m] = ld8h(&sA[cur][m * 16 + lr][kg8]);
#pragma unroll
        for (int n = 0; n < 4; n++) bb[n] = ld8h(&sB[cur][w * 64 + n * 16 + lr][kg8]);
#pragma unroll
        for (int m = 0; m < 4; m++)
#pragma unroll
            for (int n = 0; n < 4; n++)
                acc[m][n] = __builtin_amdgcn_mfma_f32_16x16x32_f16(a[m], bb[n], acc[m][n], 0, 0, 0);
    }
    // epilogue: partial[kc][row][col]
#pragma unroll
    for (int m = 0; m < 4; m++) {
#pragma unroll
        for (int n = 0; n < 4; n++) {
            int col = w * 64 + n * 16 + lr;
#pragma unroll
            for (int r = 0; r < 4; r++) {
                size_t grow = rowBase + m * 16 + g * 4 + r;
                partial[((size_t)kc * NROWS + grow) * DOUTn + col] = acc[m][n][r];
            }
        }
    }
}

// ---------------------------------------------------------------------------
// Kernel 6: out = sum of 4 partials
// ---------------------------------------------------------------------------
__global__ __launch_bounds__(256) void k_reduce(const float* __restrict__ partial,
                                                float* __restrict__ out) {
    const size_t stride = (size_t)NROWS * DOUTn;
    size_t i = ((size_t)blockIdx.x * 256 + threadIdx.x) * 4;
    f32x4 a0 = *reinterpret_cast<const f32x4*>(partial + i);
    f32x4 a1 = *reinterpret_cast<const f32x4*>(partial + stride + i);
    f32x4 a2 = *reinterpret_cast<const f32x4*>(partial + 2 * stride + i);
    f32x4 a3 = *reinterpret_cast<const f32x4*>(partial + 3 * stride + i);
    f32x4 s = (a0 + a1) + (a2 + a3);
    *reinterpret_cast<f32x4*>(out + i) = s;
}

// ---------------------------------------------------------------------------
extern "C" void kernel_launch(void* const* d_in, const int* in_sizes, int n_in,
                              void* d_out, int out_size, void* d_ws, size_t ws_size,
                              hipStream_t stream) {
    const float* dec = (const float*)d_in[0];
    const float* emb = (const float*)d_in[1];
    const int* emask = (const int*)d_in[2];
    const float* W = (const float*)d_in[3];
    const float* bias = (const float*)d_in[4];

    float* out = (float*)d_out;
    float* attn = out + (size_t)NROWS * DOUTn;

    char* wsb = (char*)d_ws;
    u16* ds_hi = (u16*)wsb;
    wsb += (size_t)NROWS * DOUTn * 2;
    u16* ds_lo = (u16*)wsb;
    wsb += (size_t)NROWS * DOUTn * 2;
    _Float16* embT = (_Float16*)wsb;
    wsb += (size_t)NB * DOUTn * TKn * 2;
    float* inv_sum = (float*)wsb;
    wsb += (size_t)NROWS * 4;
    float* partsum = (float*)wsb;
    wsb += (size_t)NKB * NROWS * 4;
    float* partial = (float*)wsb;  // 4 * 8192 * 256 fp32 = 33.5 MB

    k_embT<<<dim3(TKn / 64, DOUTn / 64, NB), 256, 0, stream>>>(emb, embT);
    k_linear<<<dim3(NROWS / 128, DOUTn / 64), 256, 0, stream>>>(dec, W, bias, ds_hi, ds_lo);
    k_scores_exp<<<dim3(TQn / 128, NKB, NB), 256, 0, stream>>>(ds_hi, ds_lo, emb, emask, attn, partsum);
    k_rowsum<<<dim3(NROWS / 256), 256, 0, stream>>>(partsum, inv_sum);
    k_pv7<<<dim3(512), 256, 0, stream>>>(attn, embT, inv_sum, partial);
    k_reduce<<<dim3((NROWS * DOUTn / 4) / 256), 256, 0, stream>>>(partial, out);
}

// Round 10
// 217.130 us; speedup vs baseline: 1.5658x; 1.0565x over previous
//
#include <hip/hip_runtime.h>
#include <hip/hip_bf16.h>
#include <hip/hip_fp16.h>

typedef unsigned short u16;
typedef __attribute__((ext_vector_type(8))) short short8;
typedef __attribute__((ext_vector_type(8))) u16 u16x8;
typedef __attribute__((ext_vector_type(4))) u16 u16x4;
typedef __attribute__((ext_vector_type(8))) _Float16 half8;
typedef __attribute__((ext_vector_type(4))) float f32x4;

#define NB 8
#define TQn 1024
#define TKn 4096
#define DINn 1024
#define DOUTn 256
#define NROWS (NB * TQn)
#define NKB (TKn / 128)
#define NKC 8           // split-K factor for PV
#define KCH (TKn / NKC) // 512
#define EXPSHIFT 40.0f
#define LP 40   // LDS row stride (u16) = 80 B: 16B-aligned rows

#define DEV static __device__ __forceinline__

DEV u16 f2bf(float x) {
    __hip_bfloat16 h = __float2bfloat16(x);
    return *reinterpret_cast<u16*>(&h);
}
DEV float bf2f(u16 u) {
    __hip_bfloat16 h;
    *reinterpret_cast<u16*>(&h) = u;
    return __bfloat162float(h);
}
DEV void split2(float x, u16& hi, u16& lo) {
    u16 h = f2bf(x);
    float hf = bf2f(h);
    hi = h;
    lo = f2bf(x - hf);
}
DEV void split4(const float4 v, u16x4& h, u16x4& l) {
    u16 h0, l0, h1, l1, h2, l2, h3, l3;
    split2(v.x, h0, l0);
    split2(v.y, h1, l1);
    split2(v.z, h2, l2);
    split2(v.w, h3, l3);
    h = (u16x4){h0, h1, h2, h3};
    l = (u16x4){l0, l1, l2, l3};
}
DEV short8 ld8s(const u16* p) { return *reinterpret_cast<const short8*>(p); }
DEV half8 ld8h(const u16* p) { return *reinterpret_cast<const half8*>(p); }
DEV void st8(u16* p, u16x8 v) { *reinterpret_cast<u16x8*>(p) = v; }

// ---------------------------------------------------------------------------
// Kernel 1: transpose+convert emb [B][TK][DOUT] fp32 -> embT [B][DOUT][TK] fp16
// ---------------------------------------------------------------------------
__global__ __launch_bounds__(256) void k_embT(const float* __restrict__ emb,
                                              _Float16* __restrict__ embT) {
    __shared__ float tile[64][65];
    const int b = blockIdx.z;
    const int k0 = blockIdx.x * 64;
    const int o0 = blockIdx.y * 64;
    const int t = threadIdx.x;
    const int c = t & 63;
    const int r0 = t >> 6;
#pragma unroll
    for (int i = 0; i < 16; i++) {
        int r = r0 + i * 4;
        tile[c][r] = emb[((size_t)b * TKn + k0 + r) * DOUTn + o0 + c];
    }
    __syncthreads();
#pragma unroll
    for (int i = 0; i < 16; i++) {
        int r = r0 + i * 4;
        embT[((size_t)b * DOUTn + o0 + r) * TKn + k0 + c] = (_Float16)tile[r][c];
    }
}

// ---------------------------------------------------------------------------
// Kernel 2: linear  decsmall = dec @ W^T + b, split into hi/lo bf16
// ---------------------------------------------------------------------------
__global__ __launch_bounds__(256) void k_linear(const float* __restrict__ dec,
                                                const float* __restrict__ W,
                                                const float* __restrict__ bias,
                                                u16* __restrict__ ds_hi,
                                                u16* __restrict__ ds_lo) {
    __shared__ u16 sAh[128][LP], sAl[128][LP], sBh[64][LP], sBl[64][LP];
    const int t = threadIdx.x;
    const int m0 = blockIdx.x * 128;
    const int n0 = blockIdx.y * 64;
    const int w = t >> 6, lane = t & 63;
    const int wr = w >> 1, wc = w & 1;
    const int lr = lane & 15, g = lane >> 4, kg8 = g * 8;

    f32x4 acc[4][2];
#pragma unroll
    for (int m = 0; m < 4; m++)
#pragma unroll
        for (int n = 0; n < 2; n++) acc[m][n] = (f32x4){0.f, 0.f, 0.f, 0.f};

    for (int k0 = 0; k0 < DINn; k0 += 32) {
        __syncthreads();
#pragma unroll
        for (int i = 0; i < 4; i++) {
            int f = i * 256 + t;
            int row = f >> 3, c4 = (f & 7) * 4;
            const float4 v = *reinterpret_cast<const float4*>(
                dec + (size_t)(m0 + row) * DINn + k0 + c4);
            u16x4 h, l;
            split4(v, h, l);
            *reinterpret_cast<u16x4*>(&sAh[row][c4]) = h;
            *reinterpret_cast<u16x4*>(&sAl[row][c4]) = l;
        }
#pragma unroll
        for (int i = 0; i < 2; i++) {
            int f = i * 256 + t;
            int row = f >> 3, c4 = (f & 7) * 4;
            const float4 v = *reinterpret_cast<const float4*>(
                W + (size_t)(n0 + row) * DINn + k0 + c4);
            u16x4 h, l;
            split4(v, h, l);
            *reinterpret_cast<u16x4*>(&sBh[row][c4]) = h;
            *reinterpret_cast<u16x4*>(&sBl[row][c4]) = l;
        }
        __syncthreads();
        short8 ah[4], al[4], bh[2], bl[2];
#pragma unroll
        for (int m = 0; m < 4; m++) {
            int row = wr * 64 + m * 16 + lr;
            ah[m] = ld8s(&sAh[row][kg8]);
            al[m] = ld8s(&sAl[row][kg8]);
        }
#pragma unroll
        for (int n = 0; n < 2; n++) {
            int row = wc * 32 + n * 16 + lr;
            bh[n] = ld8s(&sBh[row][kg8]);
            bl[n] = ld8s(&sBl[row][kg8]);
        }
#pragma unroll
        for (int m = 0; m < 4; m++)
#pragma unroll
            for (int n = 0; n < 2; n++) {
                acc[m][n] = __builtin_amdgcn_mfma_f32_16x16x32_bf16(ah[m], bh[n], acc[m][n], 0, 0, 0);
                acc[m][n] = __builtin_amdgcn_mfma_f32_16x16x32_bf16(ah[m], bl[n], acc[m][n], 0, 0, 0);
                acc[m][n] = __builtin_amdgcn_mfma_f32_16x16x32_bf16(al[m], bh[n], acc[m][n], 0, 0, 0);
            }
    }
#pragma unroll
    for (int m = 0; m < 4; m++) {
#pragma unroll
        for (int n = 0; n < 2; n++) {
            int colg = n0 + wc * 32 + n * 16 + lr;
            float bv = bias[colg];
#pragma unroll
            for (int r = 0; r < 4; r++) {
                int rowg = m0 + wr * 64 + m * 16 + g * 4 + r;
                float v = acc[m][n][r] + bv;
                u16 h, l;
                split2(v, h, l);
                ds_hi[(size_t)rowg * DOUTn + colg] = h;
                ds_lo[(size_t)rowg * DOUTn + colg] = l;
            }
        }
    }
}

// ---------------------------------------------------------------------------
// Kernel 3: scores GEMM (split 3-MFMA) + mask + p_u = exp(s - 40) nt-write
//           + per-row partial sums -> partsum[kb][row]
// ---------------------------------------------------------------------------
__global__ __launch_bounds__(256) void k_scores_exp(const u16* __restrict__ ds_hi,
                                                    const u16* __restrict__ ds_lo,
                                                    const float* __restrict__ emb,
                                                    const int* __restrict__ emask,
                                                    float* __restrict__ attn,
                                                    float* __restrict__ partsum) {
    __shared__ u16 sAh[128][LP], sAl[128][LP], sBh[128][LP], sBl[128][LP];
    __shared__ float sSum[2][128];
    const int t = threadIdx.x;
    const int flat = blockIdx.x + 8 * (blockIdx.y + 32 * blockIdx.z);
    const int b = flat & 7;
    const int rest = flat >> 3;
    const int kb = rest & 31;
    const int q0 = (rest >> 5) * 128;
    const int kb0 = kb * 128;
    const int w = t >> 6, lane = t & 63;
    const int wr = w >> 1, wc = w & 1;
    const int lr = lane & 15, g = lane >> 4, kg8 = g * 8;

    f32x4 acc[4][4];
#pragma unroll
    for (int m = 0; m < 4; m++)
#pragma unroll
        for (int n = 0; n < 4; n++) acc[m][n] = (f32x4){0.f, 0.f, 0.f, 0.f};

    for (int o0 = 0; o0 < DOUTn; o0 += 32) {
        __syncthreads();
#pragma unroll
        for (int i = 0; i < 2; i++) {
            int f8 = i * 256 + t;
            int row = f8 >> 2, c8 = (f8 & 3) * 8;
            size_t src = (size_t)(b * TQn + q0 + row) * DOUTn + o0 + c8;
            st8(&sAh[row][c8], *reinterpret_cast<const u16x8*>(ds_hi + src));
            st8(&sAl[row][c8], *reinterpret_cast<const u16x8*>(ds_lo + src));
        }
#pragma unroll
        for (int i = 0; i < 4; i++) {
            int f = i * 256 + t;
            int row = f >> 3, c4 = (f & 7) * 4;
            const float4 v = *reinterpret_cast<const float4*>(
                emb + (size_t)(b * TKn + kb0 + row) * DOUTn + o0 + c4);
            u16x4 h, l;
            split4(v, h, l);
            *reinterpret_cast<u16x4*>(&sBh[row][c4]) = h;
            *reinterpret_cast<u16x4*>(&sBl[row][c4]) = l;
        }
        __syncthreads();
        short8 ah[4], al[4], bh[4], bl[4];
#pragma unroll
        for (int m = 0; m < 4; m++) {
            int row = wr * 64 + m * 16 + lr;
            ah[m] = ld8s(&sAh[row][kg8]);
            al[m] = ld8s(&sAl[row][kg8]);
        }
#pragma unroll
        for (int n = 0; n < 4; n++) {
            int row = wc * 64 + n * 16 + lr;
            bh[n] = ld8s(&sBh[row][kg8]);
            bl[n] = ld8s(&sBl[row][kg8]);
        }
#pragma unroll
        for (int m = 0; m < 4; m++)
#pragma unroll
            for (int n = 0; n < 4; n++) {
                acc[m][n] = __builtin_amdgcn_mfma_f32_16x16x32_bf16(ah[m], bh[n], acc[m][n], 0, 0, 0);
                acc[m][n] = __builtin_amdgcn_mfma_f32_16x16x32_bf16(ah[m], bl[n], acc[m][n], 0, 0, 0);
                acc[m][n] = __builtin_amdgcn_mfma_f32_16x16x32_bf16(al[m], bh[n], acc[m][n], 0, 0, 0);
            }
    }
    const int* em = emask + (size_t)b * TKn;
    float* pout = attn + ((size_t)(b * TQn + q0)) * TKn + kb0;
    float rowAcc[4][4];
#pragma unroll
    for (int m = 0; m < 4; m++)
#pragma unroll
        for (int r = 0; r < 4; r++) rowAcc[m][r] = 0.f;

#pragma unroll
    for (int n = 0; n < 4; n++) {
        int colL = wc * 64 + n * 16 + lr;
        int mk = em[kb0 + colL];
#pragma unroll
        for (int m = 0; m < 4; m++) {
#pragma unroll
            for (int r = 0; r < 4; r++) {
                int rowL = wr * 64 + m * 16 + g * 4 + r;
                float p = mk ? __expf(acc[m][n][r] - EXPSHIFT) : 0.f;
                __builtin_nontemporal_store(p, &pout[(size_t)rowL * TKn + colL]);
                rowAcc[m][r] += p;
            }
        }
    }
#pragma unroll
    for (int m = 0; m < 4; m++) {
#pragma unroll
        for (int r = 0; r < 4; r++) {
            float v = rowAcc[m][r];
            v += __shfl_xor(v, 1);
            v += __shfl_xor(v, 2);
            v += __shfl_xor(v, 4);
            v += __shfl_xor(v, 8);
            if (lr == 0) sSum[wc][wr * 64 + m * 16 + g * 4 + r] = v;
        }
    }
    __syncthreads();
    if (t < 128) {
        partsum[(size_t)kb * NROWS + (size_t)b * TQn + q0 + t] =
            sSum[0][t] + sSum[1][t];
    }
}

// ---------------------------------------------------------------------------
// Kernel 4: inv_sum[row] = 1 / sum_kb partsum[kb][row]
// ---------------------------------------------------------------------------
__global__ __launch_bounds__(256) void k_rowsum(const float* __restrict__ partsum,
                                                float* __restrict__ inv_sum) {
    int row = blockIdx.x * 256 + threadIdx.x;
    float s = 0.f;
#pragma unroll
    for (int kb = 0; kb < NKB; kb++) s += partsum[(size_t)kb * NROWS + row];
    inv_sum[row] = 1.0f / s;
}

// ---------------------------------------------------------------------------
// Kernel 5: PV GEMM + fused attn normalize write-back.
// BIG TILE to cut logical reads: 128 q x 256 o per block, split-K x8
// (K-chunk 512, NIT=16, KT=32). 512 threads = 8 waves (2 q-halves x 4
// o-quarters), 16 MFMA/wave/iter. Double-buffered LDS, reg prefetch,
// lgkm-only raw barrier. A-transform: v = p_u * inv -> plain store to attn
// (final value) + cvt fp16 -> LDS. Epilogue: partial[kc].
// ---------------------------------------------------------------------------
__global__ __launch_bounds__(512, 4) void k_pv8(float* __restrict__ attn,
                                                const _Float16* __restrict__ embT,
                                                const float* __restrict__ inv_sum,
                                                float* __restrict__ partial) {
    __shared__ u16 sA[2][128][LP];   // 20.5 KB
    __shared__ u16 sB[2][256][LP];   // 41 KB
    __shared__ float sInv[128];
    const int t = threadIdx.x;
    const int flat = blockIdx.x;      // 0..511
    const int b = flat & 7;
    const int rest = flat >> 3;       // 0..63
    const int kc = rest & 7;
    const int q0 = (rest >> 3) * 128;
    const int w = t >> 6, lane = t & 63;
    const int lr = lane & 15, g = lane >> 4, kg8 = g * 8;
    const int wr = w >> 2, wc = w & 3;
    const int kbase = kc * KCH;
    const size_t rowBase = (size_t)b * TQn + q0;
    const u16* ebt = reinterpret_cast<const u16*>(embT);

    if (t < 128) sInv[t] = inv_sum[rowBase + t];

    // A staging: 128 rows x 32 k fp32 = 4096 f32 / 512 thr = 2 x f32x4
    const int ar = t >> 3, ac4 = (t & 7) * 4;  // i adds 64 rows

    f32x4 acc[4][4];
#pragma unroll
    for (int m = 0; m < 4; m++)
#pragma unroll
        for (int n = 0; n < 4; n++) acc[m][n] = (f32x4){0.f, 0.f, 0.f, 0.f};

    // prologue: prefetch tile 0
    f32x4 pa[2];
    u16x8 pb[2];
#pragma unroll
    for (int i = 0; i < 2; i++) {
        int row = ar + i * 64;
        pa[i] = *reinterpret_cast<const f32x4*>(attn + (rowBase + row) * TKn + kbase + ac4);
    }
#pragma unroll
    for (int i = 0; i < 2; i++) {
        int f = i * 512 + t;
        int row = f >> 2, c8 = (f & 3) * 8;
        pb[i] = *reinterpret_cast<const u16x8*>(
            ebt + (size_t)(b * DOUTn + row) * TKn + kbase + c8);
    }
    __syncthreads();  // sInv ready

    const int NIT = KCH / 32;  // 16
    for (int it = 0; it < NIT; it++) {
        const int cur = it & 1;
        const int ks = it * 32;
        // ---- commit tile it ----
#pragma unroll
        for (int i = 0; i < 2; i++) {
            int row = ar + i * 64;
            f32x4 v = pa[i] * sInv[row];
            *reinterpret_cast<f32x4*>(attn + (rowBase + row) * TKn + kbase + ks + ac4) = v;
            u16x4 hv;
            hv[0] = __builtin_bit_cast(u16, (_Float16)v[0]);
            hv[1] = __builtin_bit_cast(u16, (_Float16)v[1]);
            hv[2] = __builtin_bit_cast(u16, (_Float16)v[2]);
            hv[3] = __builtin_bit_cast(u16, (_Float16)v[3]);
            *reinterpret_cast<u16x4*>(&sA[cur][row][ac4]) = hv;
        }
#pragma unroll
        for (int i = 0; i < 2; i++) {
            int f = i * 512 + t;
            int row = f >> 2, c8 = (f & 3) * 8;
            st8(&sB[cur][row][c8], pb[i]);
        }
        // ---- raw barrier (LDS visibility only) ----
        asm volatile("s_waitcnt lgkmcnt(0)" ::: "memory");
        __builtin_amdgcn_s_barrier();
        asm volatile("" ::: "memory");
        // ---- prefetch tile it+1 ----
        if (it + 1 < NIT) {
            int ksn = ks + 32;
#pragma unroll
            for (int i = 0; i < 2; i++) {
                int row = ar + i * 64;
                pa[i] = *reinterpret_cast<const f32x4*>(
                    attn + (rowBase + row) * TKn + kbase + ksn + ac4);
            }
#pragma unroll
            for (int i = 0; i < 2; i++) {
                int f = i * 512 + t;
                int row = f >> 2, c8 = (f & 3) * 8;
                pb[i] = *reinterpret_cast<const u16x8*>(
                    ebt + (size_t)(b * DOUTn + row) * TKn + kbase + ksn + c8);
            }
        }
        // ---- compute: 16 MFMA per wave ----
        half8 a[4], bb[4];
#pragma unroll
        for (int m = 0; m < 4; m++) a[m] = ld8h(&sA[cur][wr * 64 + m * 16 + lr][kg8]);
#pragma unroll
        for (int n = 0; n < 4; n++) bb[n] = ld8h(&sB[cur][wc * 64 + n * 16 + lr][kg8]);
#pragma unroll
        for (int m = 0; m < 4; m++)
#pragma unroll
            for (int n = 0; n < 4; n++)
                acc[m][n] = __builtin_amdgcn_mfma_f32_16x16x32_f16(a[m], bb[n], acc[m][n], 0, 0, 0);
    }
    // epilogue: partial[kc][row][col]
#pragma unroll
    for (int m = 0; m < 4; m++) {
#pragma unroll
        for (int n = 0; n < 4; n++) {
            int col = wc * 64 + n * 16 + lr;
#pragma unroll
            for (int r = 0; r < 4; r++) {
                size_t grow = rowBase + wr * 64 + m * 16 + g * 4 + r;
                partial[((size_t)kc * NROWS + grow) * DOUTn + col] = acc[m][n][r];
            }
        }
    }
}

// ---------------------------------------------------------------------------
// Kernel 6: out = sum of 8 partials
// ---------------------------------------------------------------------------
__global__ __launch_bounds__(256) void k_reduce(const float* __restrict__ partial,
                                                float* __restrict__ out) {
    const size_t stride = (size_t)NROWS * DOUTn;
    size_t i = ((size_t)blockIdx.x * 256 + threadIdx.x) * 4;
    f32x4 s = (f32x4){0.f, 0.f, 0.f, 0.f};
#pragma unroll
    for (int kc = 0; kc < NKC; kc++)
        s += *reinterpret_cast<const f32x4*>(partial + kc * stride + i);
    *reinterpret_cast<f32x4*>(out + i) = s;
}

// ---------------------------------------------------------------------------
extern "C" void kernel_launch(void* const* d_in, const int* in_sizes, int n_in,
                              void* d_out, int out_size, void* d_ws, size_t ws_size,
                              hipStream_t stream) {
    const float* dec = (const float*)d_in[0];
    const float* emb = (const float*)d_in[1];
    const int* emask = (const int*)d_in[2];
    const float* W = (const float*)d_in[3];
    const float* bias = (const float*)d_in[4];

    float* out = (float*)d_out;
    float* attn = out + (size_t)NROWS * DOUTn;

    char* wsb = (char*)d_ws;
    u16* ds_hi = (u16*)wsb;
    wsb += (size_t)NROWS * DOUTn * 2;
    u16* ds_lo = (u16*)wsb;
    wsb += (size_t)NROWS * DOUTn * 2;
    _Float16* embT = (_Float16*)wsb;
    wsb += (size_t)NB * DOUTn * TKn * 2;
    float* inv_sum = (float*)wsb;
    wsb += (size_t)NROWS * 4;
    float* partsum = (float*)wsb;
    wsb += (size_t)NKB * NROWS * 4;
    float* partial = (float*)wsb;  // 8 * 8192 * 256 fp32 = 67 MB

    k_embT<<<dim3(TKn / 64, DOUTn / 64, NB), 256, 0, stream>>>(emb, embT);
    k_linear<<<dim3(NROWS / 128, DOUTn / 64), 256, 0, stream>>>(dec, W, bias, ds_hi, ds_lo);
    k_scores_exp<<<dim3(TQn / 128, NKB, NB), 256, 0, stream>>>(ds_hi, ds_lo, emb, emask, attn, partsum);
    k_rowsum<<<dim3(NROWS / 256), 256, 0, stream>>>(partsum, inv_sum);
    k_pv8<<<dim3(512), 512, 0, stream>>>(attn, embT, inv_sum, partial);
    k_reduce<<<dim3((NROWS * DOUTn / 4) / 256), 256, 0, stream>>>(partial, out);
}